// Round 1
// baseline (7708.794 us; speedup 1.0000x reference)
//
#include <hip/hip_runtime.h>
#include <math.h>

typedef unsigned int u32;
typedef unsigned long long u64;

// ---------------- level tables ----------------
__constant__ int c_W[5]   = {304,152,76,38,19};
__constant__ int c_STR[5] = {4,8,16,32,64};
__constant__ int c_SZ[5]  = {32,64,128,256,512};
__constant__ int c_S[5]   = {182400,45600,11400,2850,741};   // H*W*A
__constant__ int c_K[5]   = {1000,1000,1000,1000,741};       // min(1000, S)
__constant__ u64 c_SCOFF[5] = {0,364800,456000,478800,484500}; // doubles, per-level base (x2 images)
__constant__ int c_LOFF[5] = {0,1000,2000,3000,4000};

static const int h_W[5] = {304,152,76,38,19};
static const int h_H[5] = {200,100,50,25,13};
static const size_t h_SCOFF[5] = {0,364800,456000,478800,484500};

// ---------------- workspace layout ----------------
static constexpr size_t alignup(size_t x){ return (x + 255) & ~(size_t)255; }
static constexpr size_t N_SC   = 485982;     // total scores (both images)
static constexpr int    M_CAND = 4741;       // candidates per image
static constexpr size_t OFF_SCORE = 0;                                   // f64[N_SC]
static constexpr size_t OFF_DELTA = alignup(OFF_SCORE + N_SC*8);          // f64[N_SC*4]
static constexpr size_t OFF_THR   = alignup(OFF_DELTA + N_SC*4*8);        // u64[16]
static constexpr size_t OFF_QUOTA = OFF_THR + 128;                        // u32[16]
static constexpr size_t OFF_CNT   = OFF_QUOTA + 128;                      // u32[64]: cur[0..9], eq[16..25], vcnt[32..33]
static constexpr size_t OFF_SEL   = alignup(OFF_CNT + 256);               // u32[10][1024]
static constexpr size_t OFF_CBOX  = alignup(OFF_SEL + 10*1024*4);         // f64[2][4741][4]
static constexpr size_t OFF_CSC   = alignup(OFF_CBOX + 2ull*M_CAND*4*8);  // f64[2][4741]
static constexpr size_t OFF_SKEY  = alignup(OFF_CSC + 2ull*M_CAND*8);     // u64[2][8192]
static constexpr size_t OFF_SIDX  = alignup(OFF_SKEY + 2ull*8192*8);      // u32[2][8192]
static constexpr size_t OFF_SBOX  = alignup(OFF_SIDX + 2ull*8192*4);      // f64[2][4741][4]
static constexpr size_t OFF_SSC   = alignup(OFF_SBOX + 2ull*M_CAND*4*8);  // f64[2][4741]
static constexpr size_t OFF_MASK  = alignup(OFF_SSC + 2ull*M_CAND*8);     // u64[2][4800][75]
static constexpr size_t WS_NEED   = OFF_MASK + 2ull*4800*75*8;            // ~26 MB

__device__ __forceinline__ u64 ordkey(double s){
  u64 b = (u64)__double_as_longlong(s);
  return b ^ ((b >> 63) ? 0xFFFFFFFFFFFFFFFFULL : 0x8000000000000000ULL);
}

// ---------------- K0: init counters + sort padding ----------------
__global__ __launch_bounds__(256) void k_init(u32* cnt, u64* skey, u32* sidx){
  int t = blockIdx.x*256 + threadIdx.x;
  if (t < 64) cnt[t] = 0;
  const int npad = 8192 - M_CAND;
  if (t < 2*npad){
    int img = t / npad;
    int j = M_CAND + (t - img*npad);
    skey[(size_t)img*8192 + j] = 0ULL;
    sidx[(size_t)img*8192 + j] = 0x7FFFFFFFu;
  }
}

// ---------------- K1: fused conv3x3+ReLU+1x1(obj/delta), fp64 accumulation ----------------
// block: 256 threads = one output-channel each; 32 consecutive x positions in row y.
__global__ __launch_bounds__(256) void k_conv(
    const float* __restrict__ feat, const float* __restrict__ cw,
    const float* __restrict__ cb, const float* __restrict__ ow,
    const float* __restrict__ ob, const float* __restrict__ dwt,
    const float* __restrict__ db, double* __restrict__ score_out,
    double* __restrict__ delta_out, int H, int W)
{
  __shared__ double patch[2][3][36];   // 2 ci x 3 rows x 34(+pad) cols
  __shared__ float  w1lds[15*256];     // obj(3x256) + delta(12x256)
  __shared__ double tl[16][257];       // t transpose for 1x1, padded
  const int tid = threadIdx.x;
  const int y  = blockIdx.y;
  const int x0 = blockIdx.x * 32;
  const int n  = blockIdx.z;
  const size_t HW = (size_t)H*W;
  const float* fb = feat + (size_t)n*256*HW;
  for (int i=tid;i<15*256;i+=256) w1lds[i] = (i<768) ? ow[i] : dwt[i-768];
  double acc[32];
  #pragma unroll
  for (int p=0;p<32;p++) acc[p]=0.0;
  const int co = tid;
  for (int ci0=0; ci0<256; ci0+=2){
    __syncthreads();
    for (int e=tid;e<204;e+=256){
      int ciL = e/102, rem = e - ciL*102, ry = rem/34, cx = rem - ry*34;
      int yy = y+ry-1, xx = x0+cx-1;
      float v = 0.0f;
      if (yy>=0 && yy<H && xx>=0 && xx<W) v = fb[(size_t)(ci0+ciL)*HW + (size_t)yy*W + xx];
      patch[ciL][ry][cx] = (double)v;
    }
    double wreg[18];
    const float* wp = cw + ((size_t)co*256 + ci0)*9;
    #pragma unroll
    for (int i=0;i<18;i++) wreg[i] = (double)wp[i];
    __syncthreads();
    #pragma unroll
    for (int ciL=0;ciL<2;ciL++){
      #pragma unroll
      for (int ky=0;ky<3;ky++){
        const double* row = patch[ciL][ky];
        double w0=wreg[ciL*9+ky*3+0], w1r=wreg[ciL*9+ky*3+1], w2=wreg[ciL*9+ky*3+2];
        #pragma unroll
        for (int pc=0;pc<4;pc++){
          double r[10];
          #pragma unroll
          for (int q=0;q<10;q++) r[q] = row[pc*8+q];
          #pragma unroll
          for (int q=0;q<8;q++) acc[pc*8+q] += w0*r[q] + w1r*r[q+1] + w2*r[q+2];
        }
      }
    }
  }
  {
    double bc = (double)cb[co];
    #pragma unroll
    for (int p=0;p<32;p++){ double t = acc[p] + bc; acc[p] = t > 0.0 ? t : 0.0; }
  }
  double* so  = score_out + (size_t)n*HW*3;
  double* dlo = delta_out + (size_t)n*HW*12;
  for (int half=0; half<2; half++){
    __syncthreads();
    #pragma unroll
    for (int p=0;p<16;p++) tl[p][co] = acc[half*16+p];
    __syncthreads();
    if (tid < 240){
      int oc = tid >> 4, p = tid & 15;
      double s = 0.0;
      for (int c=0;c<256;c++) s += (double)w1lds[oc*256+c] * tl[p][c];
      int px = x0 + half*16 + p;
      if (px < W){
        size_t pos = (size_t)y*W + px;
        if (oc < 3) so[pos*3 + oc] = s + (double)ob[oc];
        else { int d = oc-3; int a = d>>2, c2 = d&3; dlo[(pos*3+a)*4 + c2] = s + (double)db[d]; }
      }
    }
  }
}

// ---------------- K2: per-(level,image) radix-select of k-th largest key ----------------
__global__ __launch_bounds__(1024) void k_radix(const double* __restrict__ score,
                                                u64* __restrict__ thr, u32* __restrict__ quota)
{
  const int u = blockIdx.x, l = u >> 1, img = u & 1;
  const int n = c_S[l], k = c_K[l];
  const int tid = threadIdx.x;
  if (n <= k){ if (tid==0){ thr[u]=0ULL; quota[u]=0u; } return; }
  const double* sc = score + c_SCOFF[l] + (size_t)img*n;
  __shared__ u32 hist[2048];
  __shared__ u32 grp[32];
  __shared__ u64 s_pref;
  __shared__ u32 s_rem;
  if (tid==0){ s_pref=0ULL; s_rem=(u32)k; }
  const int shifts[6] = {53,42,31,20,9,0};
  const int bitsA[6]  = {11,11,11,11,11,9};
  for (int p=0;p<6;p++){
    const int nb = 1 << bitsA[p];
    for (int i=tid;i<nb;i+=1024) hist[i]=0u;
    __syncthreads();
    const u64 pref = s_pref;
    const int sh = shifts[p], hb = bitsA[p];
    for (int i=tid;i<n;i+=1024){
      u64 key = ordkey(sc[i]);
      bool m = (p==0) || ((key >> (sh+hb)) == pref);
      if (m) atomicAdd(&hist[(u32)((key>>sh) & (u64)(nb-1))], 1u);
    }
    __syncthreads();
    const int per = nb >> 5;
    if (tid < 32){ u32 s=0; for (int q=0;q<per;q++) s += hist[tid*per+q]; grp[tid]=s; }
    __syncthreads();
    if (tid==0){
      u32 rem = s_rem, cum = 0;
      int g = 31;
      for (; g>0; g--){ if (cum + grp[g] >= rem) break; cum += grp[g]; }
      int b = (g+1)*per - 1;
      for (; b > g*per; b--){ if (cum + hist[b] >= rem) break; cum += hist[b]; }
      s_pref = (s_pref << hb) | (u64)b;
      s_rem = rem - cum;
    }
    __syncthreads();
  }
  if (tid==0){ thr[u] = s_pref; quota[u] = s_rem; }
}

// ---------------- K2b: compact top-k indices ----------------
__global__ __launch_bounds__(256) void k_compact(const double* __restrict__ score,
    const u64* __restrict__ thr, const u32* __restrict__ quota,
    u32* __restrict__ cnt, u32* __restrict__ sel)
{
  const int u = blockIdx.y, l = u >> 1, img = u & 1;
  const int n = c_S[l];
  const int i = blockIdx.x*256 + threadIdx.x;
  if (i >= n) return;
  const double* sc = score + c_SCOFF[l] + (size_t)img*n;
  u64 key = ordkey(sc[i]);
  u64 t = thr[u];
  bool take = false;
  if (key > t) take = true;
  else if (key == t){ if (atomicAdd(&cnt[16+u],1u) < quota[u]) take = true; }
  if (take){ u32 p = atomicAdd(&cnt[u],1u); sel[u*1024 + p] = (u32)i; }
}

// ---------------- K3: decode boxes (exact mixed fp32/fp64 like reference) ----------------
__global__ __launch_bounds__(256) void k_decode(
    const double* __restrict__ score, const double* __restrict__ delta,
    const u32* __restrict__ sel, double* __restrict__ cbox,
    double* __restrict__ csc, u64* __restrict__ skey, u32* __restrict__ sidx,
    u32* __restrict__ cnt)
{
#pragma clang fp contract(off)
  const int u = blockIdx.y, l = u >> 1, img = u & 1;
  const int slot = blockIdx.x*256 + threadIdx.x;
  if (slot >= c_K[l]) return;
  const int n = c_S[l];
  const double* sc = score + c_SCOFF[l] + (size_t)img*n;
  const double* dl = delta + (c_SCOFF[l] + (size_t)img*n)*4;
  const u32 idx = sel[u*1024 + slot];
  const double s = sc[idx];
  const double d0 = dl[(size_t)idx*4+0], d1 = dl[(size_t)idx*4+1];
  double d2 = dl[(size_t)idx*4+2], d3 = dl[(size_t)idx*4+3];
  const int pos = idx/3, a = idx - pos*3;
  const int W = c_W[l];
  const int x = pos % W, y = pos / W;
  const double rr = (a==0) ? 0.5 : ((a==1) ? 1.0 : 2.0);
  const double sz = (double)c_SZ[l];
  const double wa = sqrt(sz*sz/rr);
  const double ha = wa*rr;
  // anchors: np builds ca in fp32, shifts in fp32, adds in fp32
  const float xs = (float)(x*c_STR[l]);
  const float ys = (float)(y*c_STR[l]);
  const float ax0 = xs + (float)(-0.5*wa);
  const float ax1 = xs + (float)( 0.5*wa);
  const float ay0 = ys + (float)(-0.5*ha);
  const float ay1 = ys + (float)( 0.5*ha);
  // apply_deltas: w/h/cx/cy computed on the fp32 anchors (weak promotion), then fp64
  const float wf = ax1 - ax0;
  const float hf = ay1 - ay0;
  const float cxf = ax0 + 0.5f*wf;
  const float cyf = ay0 + 0.5f*hf;
  const double Wd = (double)wf, Hd = (double)hf, CX = (double)cxf, CY = (double)cyf;
  const double SCLAMP = 4.135166556742356;   // log(1000/16)
  if (d2 > SCLAMP) d2 = SCLAMP;
  if (d3 > SCLAMP) d3 = SCLAMP;
  double pcx = d0*Wd; pcx = pcx + CX;
  double pcy = d1*Hd; pcy = pcy + CY;
  const double pw = exp(d2)*Wd;
  const double ph = exp(d3)*Hd;
  double x0 = pcx - 0.5*pw;
  double y0 = pcy - 0.5*ph;
  double x1 = pcx + 0.5*pw;
  double y1 = pcy + 0.5*ph;
  x0 = fmin(fmax(x0, 0.0), 1216.0);
  x1 = fmin(fmax(x1, 0.0), 1216.0);
  y0 = fmin(fmax(y0, 0.0), 800.0);
  y1 = fmin(fmax(y1, 0.0), 800.0);
  const bool valid = (x1 - x0 > 0.0) && (y1 - y0 > 0.0);
  const double sm = valid ? s : -1e9;
  const int cp = c_LOFF[l] + slot;
  double* cb = cbox + ((size_t)img*M_CAND + cp)*4;
  cb[0]=x0; cb[1]=y0; cb[2]=x1; cb[3]=y1;
  csc[(size_t)img*M_CAND + cp] = sm;
  skey[(size_t)img*8192 + cp] = ordkey(sm);
  sidx[(size_t)img*8192 + cp] = (u32)cp;
  if (valid) atomicAdd(&cnt[32+img], 1u);
}

// ---------------- K4: per-image bitonic sort (desc score, asc idx) ----------------
__global__ __launch_bounds__(1024) void k_sort(u64* __restrict__ key, u32* __restrict__ idx)
{
  const int img = blockIdx.x;
  u64* k_ = key + (size_t)img*8192;
  u32* i_ = idx + (size_t)img*8192;
  const int tid = threadIdx.x;
  for (int k=2;k<=8192;k<<=1){
    for (int j=k>>1;j>0;j>>=1){
      for (int i=tid;i<8192;i+=1024){
        int l = i ^ j;
        if (l > i){
          u64 ka = k_[i], kb = k_[l];
          u32 ia = i_[i], ib = i_[l];
          bool before = (ka > kb) || (ka == kb && ia < ib);
          bool up = (i & k) == 0;
          if (up ? !before : before){
            k_[i]=kb; k_[l]=ka; i_[i]=ib; i_[l]=ia;
          }
        }
      }
      __syncthreads();
    }
  }
}

// ---------------- K4b: gather sorted boxes/scores ----------------
__global__ __launch_bounds__(256) void k_gather(const u32* __restrict__ sidx,
    const double* __restrict__ cbox, const double* __restrict__ csc,
    double* __restrict__ sbox, double* __restrict__ ssc)
{
  int t = blockIdx.x*256 + threadIdx.x;
  if (t >= 2*M_CAND) return;
  int img = t / M_CAND, j = t - img*M_CAND;
  u32 b = sidx[(size_t)img*8192 + j];
  const double* cb = cbox + ((size_t)img*M_CAND + b)*4;
  double* sb = sbox + ((size_t)img*M_CAND + j)*4;
  sb[0]=cb[0]; sb[1]=cb[1]; sb[2]=cb[2]; sb[3]=cb[3];
  ssc[(size_t)img*M_CAND + j] = csc[(size_t)img*M_CAND + b];
}

// ---------------- K5: pairwise IoU suppression bitmask ----------------
__global__ __launch_bounds__(256) void k_iou(const double* __restrict__ sbox, u64* __restrict__ mask)
{
#pragma clang fp contract(off)
  const int jb = blockIdx.x, ib = blockIdx.y, img = blockIdx.z;
  if (jb < ib) return;
  __shared__ double ibx[64][4];
  const int tid = threadIdx.x;
  const int lane = tid & 63, wv = tid >> 6;
  if (tid < 64){
    int ig = ib*64 + tid;
    if (ig < M_CAND){
      const double* b = sbox + ((size_t)img*M_CAND + ig)*4;
      ibx[tid][0]=b[0]; ibx[tid][1]=b[1]; ibx[tid][2]=b[2]; ibx[tid][3]=b[3];
    } else { ibx[tid][0]=0; ibx[tid][1]=0; ibx[tid][2]=0; ibx[tid][3]=0; }
  }
  const int jg = jb*64 + lane;
  double jx0=0,jy0=0,jx1=0,jy1=0;
  if (jg < M_CAND){
    const double* b = sbox + ((size_t)img*M_CAND + jg)*4;
    jx0=b[0]; jy0=b[1]; jx1=b[2]; jy1=b[3];
  }
  const double ja = (jx1-jx0)*(jy1-jy0);
  __syncthreads();
  for (int s=0;s<16;s++){
    const int il = wv*16 + s;
    const int ig = ib*64 + il;
    double bx0=ibx[il][0], by0=ibx[il][1], bx1=ibx[il][2], by1=ibx[il][3];
    double lt0 = bx0 > jx0 ? bx0 : jx0;
    double lt1 = by0 > jy0 ? by0 : jy0;
    double rb0 = bx1 < jx1 ? bx1 : jx1;
    double rb1 = by1 < jy1 ? by1 : jy1;
    double w = rb0-lt0; if (w<0.0) w=0.0;
    double h = rb1-lt1; if (h<0.0) h=0.0;
    double inter = w*h;
    double ia = (bx1-bx0)*(by1-by0);
    double un = ia + ja - inter; if (un < 1e-9) un = 1e-9;
    bool bit = (jg > ig) && (jg < M_CAND) && (inter/un > 0.7);
    u64 m = __ballot(bit);
    if (lane == 0) mask[((size_t)img*4800 + ig)*75 + jb] = m;
  }
}

// ---------------- K6: chunked greedy scan + output ----------------
__global__ __launch_bounds__(256) void k_nms(const u64* __restrict__ mask,
    const double* __restrict__ sbox, const double* __restrict__ ssc,
    const u32* __restrict__ cnt, float* __restrict__ out)
{
  const int img = blockIdx.x;
  const int tid = threadIdx.x;
  __shared__ u64 remv[75];
  __shared__ u64 diag[64];
  __shared__ int keep[1000];
  __shared__ int ck[64];
  __shared__ int s_kc, s_nk, s_done;
  if (tid < 75) remv[tid] = 0ULL;
  if (tid == 0){ s_kc = 0; s_done = 0; }
  int vc = (int)cnt[32+img]; if (vc > M_CAND) vc = M_CAND;
  const u64* mrow = mask + (size_t)img*4800*75;
  __syncthreads();
  for (int c=0; c<75; c++){
    if (c*64 >= vc) break;
    if (tid < 64) diag[tid] = mrow[(size_t)(c*64+tid)*75 + c];
    __syncthreads();
    if (tid == 0){
      u64 w = remv[c];
      int kc = s_kc, nk = 0;
      int lim = vc - c*64; if (lim > 64) lim = 64;
      for (int k=0;k<lim;k++){
        if (!((w >> k) & 1ULL)){
          int idx = c*64 + k;
          keep[kc] = idx;
          ck[nk++] = idx;
          kc++;
          if (kc >= 1000) break;
          w |= diag[k];
        }
      }
      s_kc = kc; s_nk = nk;
      if (kc >= 1000) s_done = 1;
    }
    __syncthreads();
    if (s_done) break;
    const int nk = s_nk;
    if (nk > 0){
      for (int c2 = c+1+tid; c2 < 75; c2 += 256){
        u64 a = remv[c2];
        for (int q=0;q<nk;q++) a |= mrow[(size_t)ck[q]*75 + c2];
        remv[c2] = a;
      }
    }
    __syncthreads();
  }
  __syncthreads();
  int kc = s_kc; if (kc > 1000) kc = 1000;
  for (int r = tid; r < 1000; r += 256){
    float v0=0.f,v1=0.f,v2=0.f,v3=0.f,v4=-1e9f;
    if (r < kc){
      int idx = keep[r];
      const double* b = sbox + ((size_t)img*M_CAND + idx)*4;
      v0=(float)b[0]; v1=(float)b[1]; v2=(float)b[2]; v3=(float)b[3];
      v4=(float)ssc[(size_t)img*M_CAND + idx];
    }
    float* o = out + ((size_t)img*1000 + r)*5;
    o[0]=v0; o[1]=v1; o[2]=v2; o[3]=v3; o[4]=v4;
  }
}

// ---------------- host ----------------
extern "C" void kernel_launch(void* const* d_in, const int* in_sizes, int n_in,
                              void* d_out, int out_size, void* d_ws, size_t ws_size,
                              hipStream_t stream)
{
  const float* feat[5];
  for (int i=0;i<5;i++) feat[i] = (const float*)d_in[i];
  const float* cw  = (const float*)d_in[5];
  const float* cb  = (const float*)d_in[6];
  const float* ow  = (const float*)d_in[7];
  const float* ob  = (const float*)d_in[8];
  const float* dwt = (const float*)d_in[9];
  const float* db  = (const float*)d_in[10];
  float* out = (float*)d_out;
  char* ws = (char*)d_ws;
  if (ws_size < WS_NEED) return;  // fail loudly via wrong output rather than corrupt

  double* score = (double*)(ws + OFF_SCORE);
  double* delta = (double*)(ws + OFF_DELTA);
  u64*    thr   = (u64*)(ws + OFF_THR);
  u32*    quota = (u32*)(ws + OFF_QUOTA);
  u32*    cnt   = (u32*)(ws + OFF_CNT);
  u32*    sel   = (u32*)(ws + OFF_SEL);
  double* cbox  = (double*)(ws + OFF_CBOX);
  double* csc   = (double*)(ws + OFF_CSC);
  u64*    skey  = (u64*)(ws + OFF_SKEY);
  u32*    sidx  = (u32*)(ws + OFF_SIDX);
  double* sbox  = (double*)(ws + OFF_SBOX);
  double* ssc   = (double*)(ws + OFF_SSC);
  u64*    mask  = (u64*)(ws + OFF_MASK);

  k_init<<<27,256,0,stream>>>(cnt, skey, sidx);
  for (int l=0;l<5;l++){
    dim3 g((h_W[l]+31)/32, h_H[l], 2);
    k_conv<<<g,256,0,stream>>>(feat[l], cw, cb, ow, ob, dwt, db,
                               score + h_SCOFF[l], delta + h_SCOFF[l]*4,
                               h_H[l], h_W[l]);
  }
  k_radix<<<10,1024,0,stream>>>(score, thr, quota);
  k_compact<<<dim3(713,10),256,0,stream>>>(score, thr, quota, cnt, sel);
  k_decode<<<dim3(4,10),256,0,stream>>>(score, delta, sel, cbox, csc, skey, sidx, cnt);
  k_sort<<<2,1024,0,stream>>>(skey, sidx);
  k_gather<<<38,256,0,stream>>>(sidx, cbox, csc, sbox, ssc);
  k_iou<<<dim3(75,75,2),256,0,stream>>>(sbox, mask);
  k_nms<<<2,256,0,stream>>>(mask, sbox, ssc, cnt, out);
}

// Round 2
// 7073.318 us; speedup vs baseline: 1.0898x; 1.0898x over previous
//
#include <hip/hip_runtime.h>
#include <math.h>

typedef unsigned int u32;
typedef unsigned long long u64;

// ---------------- level tables ----------------
__constant__ int c_W[5]   = {304,152,76,38,19};
__constant__ int c_H[5]   = {200,100,50,25,13};
__constant__ int c_STR[5] = {4,8,16,32,64};
__constant__ int c_SZ[5]  = {32,64,128,256,512};
__constant__ int c_S[5]   = {182400,45600,11400,2850,741};   // H*W*A
__constant__ int c_K1[5]  = {1024,1024,1024,1024,741};       // selection size (margin 24)
__constant__ int c_K2[5]  = {1000,1000,1000,1000,741};       // per-level keep
__constant__ u64 c_SCOFF[5] = {0,364800,456000,478800,484500}; // per-level base (x2 images)
__constant__ int c_LOFF[5] = {0,1000,2000,3000,4000};

static const int h_W[5] = {304,152,76,38,19};
static const int h_H[5] = {200,100,50,25,13};
static const size_t h_SCOFF[5] = {0,364800,456000,478800,484500};

// ---------------- workspace layout ----------------
static constexpr size_t alignup(size_t x){ return (x + 255) & ~(size_t)255; }
static constexpr size_t N_SC   = 485982;     // total scores (both images)
static constexpr int    M_CAND = 4741;       // candidates per image
static constexpr size_t OFF_ASC   = 0;                                    // f32[N_SC]
static constexpr size_t OFF_THR   = alignup(OFF_ASC + N_SC*4);            // u32[16]
static constexpr size_t OFF_QUOTA = OFF_THR + 64;                         // u32[16]
static constexpr size_t OFF_CNT   = OFF_QUOTA + 64;                       // u32[64]: cur[0..9], eq[16..25], vcnt[32..33]
static constexpr size_t OFF_SEL   = alignup(OFF_CNT + 256);               // u32[10][1024]
static constexpr size_t OFF_RSC   = alignup(OFF_SEL + 10*1024*4);         // f64[10][1024]
static constexpr size_t OFF_RDL   = alignup(OFF_RSC + 10*1024*8);         // f64[10][1024][4]
static constexpr size_t OFF_SORD  = alignup(OFF_RDL + 10*1024*4*8);       // u32[10][1024]
static constexpr size_t OFF_CBOX  = alignup(OFF_SORD + 10*1024*4);        // f64[2][4741][4]
static constexpr size_t OFF_CSC   = alignup(OFF_CBOX + 2ull*M_CAND*4*8);  // f64[2][4741]
static constexpr size_t OFF_SKEY  = alignup(OFF_CSC + 2ull*M_CAND*8);     // u64[2][8192]
static constexpr size_t OFF_SIDX  = alignup(OFF_SKEY + 2ull*8192*8);      // u32[2][8192]
static constexpr size_t OFF_SBOX  = alignup(OFF_SIDX + 2ull*8192*4);      // f64[2][4741][4]
static constexpr size_t OFF_SSC   = alignup(OFF_SBOX + 2ull*M_CAND*4*8);  // f64[2][4741]
static constexpr size_t OFF_MASK  = alignup(OFF_SSC + 2ull*M_CAND*8);     // u64[2][4800][75]
static constexpr size_t WS_NEED   = OFF_MASK + 2ull*4800*75*8;            // ~9 MB

__device__ __forceinline__ u64 ordkey(double s){
  u64 b = (u64)__double_as_longlong(s);
  return b ^ ((b >> 63) ? 0xFFFFFFFFFFFFFFFFULL : 0x8000000000000000ULL);
}
__device__ __forceinline__ u32 ordkey32(float s){
  u32 b = __float_as_uint(s);
  return b ^ ((b >> 31) ? 0xFFFFFFFFu : 0x80000000u);
}

// ---------------- K0: init counters + sort padding ----------------
__global__ __launch_bounds__(256) void k_init(u32* cnt, u64* skey, u32* sidx){
  int t = blockIdx.x*256 + threadIdx.x;
  if (t < 64) cnt[t] = 0;
  const int npad = 8192 - M_CAND;
  if (t < 2*npad){
    int img = t / npad;
    int j = M_CAND + (t - img*npad);
    skey[(size_t)img*8192 + j] = 0ULL;
    sidx[(size_t)img*8192 + j] = 0x7FFFFFFFu;
  }
}

// ---------------- K1: fp32 approx conv3x3+ReLU+1x1(obj only) ----------------
// block: 256 threads = one intermediate channel each; 32 x positions in row y.
__global__ __launch_bounds__(256) void k_conv32(
    const float* __restrict__ feat, const float* __restrict__ cw,
    const float* __restrict__ cb, const float* __restrict__ ow,
    const float* __restrict__ ob, float* __restrict__ score_out,
    int H, int W)
{
  __shared__ float patch[4][3][36];
  __shared__ float w1[768];            // obj 3x256
  __shared__ float tl[16][257];
  const int tid = threadIdx.x;
  const int y  = blockIdx.y;
  const int x0 = blockIdx.x * 32;
  const int n  = blockIdx.z;
  const size_t HW = (size_t)H*W;
  const float* fb = feat + (size_t)n*256*HW;
  for (int i=tid;i<768;i+=256) w1[i] = ow[i];
  float acc[32];
  #pragma unroll
  for (int p=0;p<32;p++) acc[p]=0.0f;
  for (int ci0=0; ci0<256; ci0+=4){
    __syncthreads();
    for (int e=tid;e<408;e+=256){
      int ciL = e/102, rem = e - ciL*102, ry = rem/34, cx = rem - ry*34;
      int yy = y+ry-1, xx = x0+cx-1;
      float v = 0.0f;
      if (yy>=0 && yy<H && xx>=0 && xx<W) v = fb[(size_t)(ci0+ciL)*HW + (size_t)yy*W + xx];
      patch[ciL][ry][cx] = v;
    }
    float wreg[36];
    const float* wp = cw + ((size_t)tid*256 + ci0)*9;
    #pragma unroll
    for (int i=0;i<36;i++) wreg[i] = wp[i];
    __syncthreads();
    #pragma unroll
    for (int ciL=0;ciL<4;ciL++){
      #pragma unroll
      for (int ky=0;ky<3;ky++){
        const float* row = patch[ciL][ky];
        float w0=wreg[ciL*9+ky*3+0], w1r=wreg[ciL*9+ky*3+1], w2=wreg[ciL*9+ky*3+2];
        #pragma unroll
        for (int pc=0;pc<4;pc++){
          float r[10];
          #pragma unroll
          for (int q=0;q<10;q++) r[q] = row[pc*8+q];
          #pragma unroll
          for (int q=0;q<8;q++) acc[pc*8+q] += w0*r[q] + w1r*r[q+1] + w2*r[q+2];
        }
      }
    }
  }
  {
    float bc = cb[tid];
    #pragma unroll
    for (int p=0;p<32;p++){ float t = acc[p] + bc; acc[p] = t > 0.0f ? t : 0.0f; }
  }
  float* so = score_out + (size_t)n*HW*3;
  for (int half=0; half<2; half++){
    __syncthreads();
    #pragma unroll
    for (int p=0;p<16;p++) tl[p][tid] = acc[half*16+p];
    __syncthreads();
    if (tid < 48){
      int oc = tid >> 4, p = tid & 15;
      float s = 0.0f;
      for (int c=0;c<256;c++) s += w1[oc*256+c] * tl[p][c];
      int px = x0 + half*16 + p;
      if (px < W){
        size_t pos = (size_t)y*W + px;
        so[pos*3 + oc] = s + ob[oc];
      }
    }
  }
}

// ---------------- K2: per-(level,image) radix-select of K1-th largest fp32 key ----------------
__global__ __launch_bounds__(1024) void k_radix32(const float* __restrict__ ascore,
                                                  u32* __restrict__ thr, u32* __restrict__ quota)
{
  const int u = blockIdx.x, l = u >> 1, img = u & 1;
  const int n = c_S[l], k = c_K1[l];
  const int tid = threadIdx.x;
  if (n <= k){ if (tid==0){ thr[u]=0u; quota[u]=0xFFFFFFFFu; } return; }
  const float* sc = ascore + c_SCOFF[l] + (size_t)img*n;
  __shared__ u32 hist[2048];
  __shared__ u32 grp[32];
  __shared__ u32 s_pref;
  __shared__ u32 s_rem;
  if (tid==0){ s_pref=0u; s_rem=(u32)k; }
  const int shifts[3] = {21,10,0};
  const int bitsA[3]  = {11,11,10};
  for (int p=0;p<3;p++){
    const int nb = 1 << bitsA[p];
    for (int i=tid;i<nb;i+=1024) hist[i]=0u;
    __syncthreads();
    const u32 pref = s_pref;
    const int sh = shifts[p], hb = bitsA[p];
    for (int i=tid;i<n;i+=1024){
      u32 key = ordkey32(sc[i]);
      bool m = (p==0) || ((key >> (sh+hb)) == pref);
      if (m) atomicAdd(&hist[(key>>sh) & (u32)(nb-1)], 1u);
    }
    __syncthreads();
    const int per = nb >> 5;
    if (tid < 32){ u32 s=0; for (int q=0;q<per;q++) s += hist[tid*per+q]; grp[tid]=s; }
    __syncthreads();
    if (tid==0){
      u32 rem = s_rem, cum = 0;
      int g = 31;
      for (; g>0; g--){ if (cum + grp[g] >= rem) break; cum += grp[g]; }
      int b = (g+1)*per - 1;
      for (; b > g*per; b--){ if (cum + hist[b] >= rem) break; cum += hist[b]; }
      s_pref = (s_pref << hb) | (u32)b;
      s_rem = rem - cum;
    }
    __syncthreads();
  }
  if (tid==0){ thr[u] = s_pref; quota[u] = s_rem; }
}

// ---------------- K2b: compact selected indices ----------------
__global__ __launch_bounds__(256) void k_compact32(const float* __restrict__ ascore,
    const u32* __restrict__ thr, const u32* __restrict__ quota,
    u32* __restrict__ cnt, u32* __restrict__ sel)
{
  const int u = blockIdx.y, l = u >> 1, img = u & 1;
  const int n = c_S[l];
  const int i = blockIdx.x*256 + threadIdx.x;
  if (i >= n) return;
  const float* sc = ascore + c_SCOFF[l] + (size_t)img*n;
  u32 key = ordkey32(sc[i]);
  u32 q = quota[u];
  bool take = false;
  if (q == 0xFFFFFFFFu) take = true;           // n <= k: take all
  else {
    u32 t = thr[u];
    if (key > t) take = true;
    else if (key == t){ if (atomicAdd(&cnt[16+u],1u) < q) take = true; }
  }
  if (take){ u32 p = atomicAdd(&cnt[u],1u); if (p < 1024u) sel[u*1024 + p] = (u32)i; }
}

// ---------------- K3: fp64 recompute of t + obj + deltas at selected positions ----------------
// block = 8 entries; 256 threads = intermediate channel co.
__global__ __launch_bounds__(256) void k_recompute(
    const float* __restrict__ f2, const float* __restrict__ f3,
    const float* __restrict__ f4, const float* __restrict__ f5,
    const float* __restrict__ f6,
    const float* __restrict__ cw, const float* __restrict__ cb,
    const float* __restrict__ ow, const float* __restrict__ ob,
    const float* __restrict__ dwt, const float* __restrict__ db,
    const u32* __restrict__ sel, const u32* __restrict__ cnt,
    double* __restrict__ rsc, double* __restrict__ rdl)
{
  const int u = blockIdx.y, l = u >> 1, img = u & 1;
  const int j0 = blockIdx.x * 8;
  const int cu = (int)cnt[u];
  if (j0 >= cu) return;
  const int W = c_W[l], H = c_H[l];
  const size_t HW = (size_t)W*H;
  const float* fl = (l==0)?f2:(l==1)?f3:(l==2)?f4:(l==3)?f5:f6;
  const float* fb = fl + (size_t)img*256*HW;
  __shared__ float  sp[8*576];       // 18.4 KB: patch chunk (64 ci x 9 taps) x 8 entries
  __shared__ double tl2[8][257];     // 16.4 KB
  __shared__ int sx[8], sy[8], sa[8], sv[8];
  const int tid = threadIdx.x;
  if (tid < 8){
    int j = j0 + tid; int ok = (j < cu) ? 1 : 0;
    u32 i = ok ? sel[u*1024 + j] : 0u;
    int pos = (int)(i/3u);
    sa[tid] = (int)i - pos*3; sx[tid] = pos % W; sy[tid] = pos / W; sv[tid] = ok;
  }
  double acc[8];
  #pragma unroll
  for (int e=0;e<8;e++) acc[e]=0.0;
  __syncthreads();
  for (int ci0=0; ci0<256; ci0+=64){
    for (int el=tid; el<4608; el+=256){
      int e = el/576, r = el - e*576;
      int ci = r/9, q = r - ci*9, ky = q/3, kx = q - ky*3;
      int yy = sy[e]+ky-1, xx = sx[e]+kx-1;
      float v = 0.0f;
      if (yy>=0 && yy<H && xx>=0 && xx<W) v = fb[(size_t)(ci0+ci)*HW + (size_t)yy*W + xx];
      sp[el] = v;
    }
    __syncthreads();
    const float* wq = cw + (size_t)tid*2304 + (size_t)ci0*9;
    for (int kk=0; kk<576; kk+=4){
      float4 w4 = *(const float4*)(wq + kk);
      #pragma unroll
      for (int e=0;e<8;e++){
        float4 p4 = *(const float4*)(sp + e*576 + kk);
        acc[e] += (double)w4.x*(double)p4.x;
        acc[e] += (double)w4.y*(double)p4.y;
        acc[e] += (double)w4.z*(double)p4.z;
        acc[e] += (double)w4.w*(double)p4.w;
      }
    }
    __syncthreads();
  }
  {
    double bc = (double)cb[tid];
    #pragma unroll
    for (int e=0;e<8;e++){ double t = acc[e] + bc; tl2[e][tid] = t > 0.0 ? t : 0.0; }
  }
  __syncthreads();
  if (tid < 40){
    int e = tid/5, q = tid - e*5;
    if (sv[e]){
      int a = sa[e];
      const float* wv = (q==0) ? (ow + a*256) : (dwt + (size_t)(a*4 + q-1)*256);
      double bias = (q==0) ? (double)ob[a] : (double)db[a*4 + q-1];
      double s = 0.0;
      for (int c=0;c<256;c++) s += (double)wv[c]*tl2[e][c];
      s += bias;
      int j = j0 + e;
      if (q==0) rsc[(size_t)u*1024 + j] = s;
      else      rdl[((size_t)u*1024 + j)*4 + (q-1)] = s;
    }
  }
}

// ---------------- K3b: per-(level,image) bitonic sort of 1024 by exact fp64 score ----------------
__global__ __launch_bounds__(256) void k_sort1024(const double* __restrict__ rsc,
    const u32* __restrict__ cnt, u32* __restrict__ sord)
{
  const int u = blockIdx.x;
  const int cu = (int)cnt[u];
  const int tid = threadIdx.x;
  __shared__ u64 kk[1024];
  __shared__ u32 pp[1024];
  for (int i=tid;i<1024;i+=256){
    if (i < cu){ kk[i] = ordkey(rsc[(size_t)u*1024 + i]); pp[i] = (u32)i; }
    else       { kk[i] = 0ULL; pp[i] = 0xFFFFFFFFu; }
  }
  __syncthreads();
  for (int k=2;k<=1024;k<<=1){
    for (int j=k>>1;j>0;j>>=1){
      for (int i=tid;i<1024;i+=256){
        int l2 = i ^ j;
        if (l2 > i){
          u64 ka = kk[i], kb = kk[l2];
          u32 ia = pp[i], ib = pp[l2];
          bool before = (ka > kb) || (ka == kb && ia < ib);
          bool up = (i & k) == 0;
          if (up ? !before : before){
            kk[i]=kb; kk[l2]=ka; pp[i]=ib; pp[l2]=ia;
          }
        }
      }
      __syncthreads();
    }
  }
  for (int i=tid;i<1024;i+=256) sord[(size_t)u*1024 + i] = pp[i];
}

// ---------------- K4: decode boxes (exact mixed fp32/fp64 like reference) ----------------
__global__ __launch_bounds__(256) void k_decode(
    const double* __restrict__ rsc, const double* __restrict__ rdl,
    const u32* __restrict__ sel, const u32* __restrict__ sord,
    double* __restrict__ cbox, double* __restrict__ csc,
    u64* __restrict__ skey, u32* __restrict__ sidx, u32* __restrict__ cnt)
{
#pragma clang fp contract(off)
  const int u = blockIdx.y, l = u >> 1, img = u & 1;
  const int slot = blockIdx.x*256 + threadIdx.x;
  if (slot >= c_K2[l]) return;
  const u32 entry = sord[(size_t)u*1024 + slot];
  const u32 idx = sel[u*1024 + entry];
  const double s = rsc[(size_t)u*1024 + entry];
  const double d0 = rdl[((size_t)u*1024+entry)*4+0], d1 = rdl[((size_t)u*1024+entry)*4+1];
  double d2 = rdl[((size_t)u*1024+entry)*4+2], d3 = rdl[((size_t)u*1024+entry)*4+3];
  const int pos = (int)(idx/3u), a = (int)idx - pos*3;
  const int W = c_W[l];
  const int x = pos % W, y = pos / W;
  const double rr = (a==0) ? 0.5 : ((a==1) ? 1.0 : 2.0);
  const double sz = (double)c_SZ[l];
  const double wa = sqrt(sz*sz/rr);
  const double ha = wa*rr;
  // anchors: np builds ca in fp32, shifts in fp32, adds in fp32
  const float xs = (float)(x*c_STR[l]);
  const float ys = (float)(y*c_STR[l]);
  const float ax0 = xs + (float)(-0.5*wa);
  const float ax1 = xs + (float)( 0.5*wa);
  const float ay0 = ys + (float)(-0.5*ha);
  const float ay1 = ys + (float)( 0.5*ha);
  const float wf = ax1 - ax0;
  const float hf = ay1 - ay0;
  const float cxf = ax0 + 0.5f*wf;
  const float cyf = ay0 + 0.5f*hf;
  const double Wd = (double)wf, Hd = (double)hf, CX = (double)cxf, CY = (double)cyf;
  const double SCLAMP = 4.135166556742356;   // log(1000/16)
  if (d2 > SCLAMP) d2 = SCLAMP;
  if (d3 > SCLAMP) d3 = SCLAMP;
  double pcx = d0*Wd; pcx = pcx + CX;
  double pcy = d1*Hd; pcy = pcy + CY;
  const double pw = exp(d2)*Wd;
  const double ph = exp(d3)*Hd;
  double x0 = pcx - 0.5*pw;
  double y0 = pcy - 0.5*ph;
  double x1 = pcx + 0.5*pw;
  double y1 = pcy + 0.5*ph;
  x0 = fmin(fmax(x0, 0.0), 1216.0);
  x1 = fmin(fmax(x1, 0.0), 1216.0);
  y0 = fmin(fmax(y0, 0.0), 800.0);
  y1 = fmin(fmax(y1, 0.0), 800.0);
  const bool valid = (x1 - x0 > 0.0) && (y1 - y0 > 0.0);
  const double sm = valid ? s : -1e9;
  const int cp = c_LOFF[l] + slot;
  double* cb = cbox + ((size_t)img*M_CAND + cp)*4;
  cb[0]=x0; cb[1]=y0; cb[2]=x1; cb[3]=y1;
  csc[(size_t)img*M_CAND + cp] = sm;
  skey[(size_t)img*8192 + cp] = ordkey(sm);
  sidx[(size_t)img*8192 + cp] = (u32)cp;
  if (valid) atomicAdd(&cnt[32+img], 1u);
}

// ---------------- K5: per-image bitonic sort (desc score, asc idx) ----------------
__global__ __launch_bounds__(1024) void k_sort(u64* __restrict__ key, u32* __restrict__ idx)
{
  const int img = blockIdx.x;
  u64* k_ = key + (size_t)img*8192;
  u32* i_ = idx + (size_t)img*8192;
  const int tid = threadIdx.x;
  for (int k=2;k<=8192;k<<=1){
    for (int j=k>>1;j>0;j>>=1){
      for (int i=tid;i<8192;i+=1024){
        int l = i ^ j;
        if (l > i){
          u64 ka = k_[i], kb = k_[l];
          u32 ia = i_[i], ib = i_[l];
          bool before = (ka > kb) || (ka == kb && ia < ib);
          bool up = (i & k) == 0;
          if (up ? !before : before){
            k_[i]=kb; k_[l]=ka; i_[i]=ib; i_[l]=ia;
          }
        }
      }
      __syncthreads();
    }
  }
}

// ---------------- K5b: gather sorted boxes/scores ----------------
__global__ __launch_bounds__(256) void k_gather(const u32* __restrict__ sidx,
    const double* __restrict__ cbox, const double* __restrict__ csc,
    double* __restrict__ sbox, double* __restrict__ ssc)
{
  int t = blockIdx.x*256 + threadIdx.x;
  if (t >= 2*M_CAND) return;
  int img = t / M_CAND, j = t - img*M_CAND;
  u32 b = sidx[(size_t)img*8192 + j];
  const double* cb = cbox + ((size_t)img*M_CAND + b)*4;
  double* sb = sbox + ((size_t)img*M_CAND + j)*4;
  sb[0]=cb[0]; sb[1]=cb[1]; sb[2]=cb[2]; sb[3]=cb[3];
  ssc[(size_t)img*M_CAND + j] = csc[(size_t)img*M_CAND + b];
}

// ---------------- K6: pairwise IoU suppression bitmask ----------------
__global__ __launch_bounds__(256) void k_iou(const double* __restrict__ sbox, u64* __restrict__ mask)
{
#pragma clang fp contract(off)
  const int jb = blockIdx.x, ib = blockIdx.y, img = blockIdx.z;
  if (jb < ib) return;
  __shared__ double ibx[64][4];
  const int tid = threadIdx.x;
  const int lane = tid & 63, wv = tid >> 6;
  if (tid < 64){
    int ig = ib*64 + tid;
    if (ig < M_CAND){
      const double* b = sbox + ((size_t)img*M_CAND + ig)*4;
      ibx[tid][0]=b[0]; ibx[tid][1]=b[1]; ibx[tid][2]=b[2]; ibx[tid][3]=b[3];
    } else { ibx[tid][0]=0; ibx[tid][1]=0; ibx[tid][2]=0; ibx[tid][3]=0; }
  }
  const int jg = jb*64 + lane;
  double jx0=0,jy0=0,jx1=0,jy1=0;
  if (jg < M_CAND){
    const double* b = sbox + ((size_t)img*M_CAND + jg)*4;
    jx0=b[0]; jy0=b[1]; jx1=b[2]; jy1=b[3];
  }
  const double ja = (jx1-jx0)*(jy1-jy0);
  __syncthreads();
  for (int s=0;s<16;s++){
    const int il = wv*16 + s;
    const int ig = ib*64 + il;
    double bx0=ibx[il][0], by0=ibx[il][1], bx1=ibx[il][2], by1=ibx[il][3];
    double lt0 = bx0 > jx0 ? bx0 : jx0;
    double lt1 = by0 > jy0 ? by0 : jy0;
    double rb0 = bx1 < jx1 ? bx1 : jx1;
    double rb1 = by1 < jy1 ? by1 : jy1;
    double w = rb0-lt0; if (w<0.0) w=0.0;
    double h = rb1-lt1; if (h<0.0) h=0.0;
    double inter = w*h;
    double ia = (bx1-bx0)*(by1-by0);
    double un = ia + ja - inter; if (un < 1e-9) un = 1e-9;
    bool bit = (jg > ig) && (jg < M_CAND) && (inter/un > 0.7);
    u64 m = __ballot(bit);
    if (lane == 0) mask[((size_t)img*4800 + ig)*75 + jb] = m;
  }
}

// ---------------- K7: chunked greedy scan + output ----------------
__global__ __launch_bounds__(256) void k_nms(const u64* __restrict__ mask,
    const double* __restrict__ sbox, const double* __restrict__ ssc,
    const u32* __restrict__ cnt, float* __restrict__ out)
{
  const int img = blockIdx.x;
  const int tid = threadIdx.x;
  __shared__ u64 remv[75];
  __shared__ u64 diag[64];
  __shared__ int keep[1000];
  __shared__ int ck[64];
  __shared__ int s_kc, s_nk, s_done;
  if (tid < 75) remv[tid] = 0ULL;
  if (tid == 0){ s_kc = 0; s_done = 0; }
  int vc = (int)cnt[32+img]; if (vc > M_CAND) vc = M_CAND;
  const u64* mrow = mask + (size_t)img*4800*75;
  __syncthreads();
  for (int c=0; c<75; c++){
    if (c*64 >= vc) break;
    if (tid < 64) diag[tid] = mrow[(size_t)(c*64+tid)*75 + c];
    __syncthreads();
    if (tid == 0){
      u64 w = remv[c];
      int kc = s_kc, nk = 0;
      int lim = vc - c*64; if (lim > 64) lim = 64;
      for (int k=0;k<lim;k++){
        if (!((w >> k) & 1ULL)){
          int idx = c*64 + k;
          keep[kc] = idx;
          ck[nk++] = idx;
          kc++;
          if (kc >= 1000) break;
          w |= diag[k];
        }
      }
      s_kc = kc; s_nk = nk;
      if (kc >= 1000) s_done = 1;
    }
    __syncthreads();
    if (s_done) break;
    const int nk = s_nk;
    if (nk > 0){
      for (int c2 = c+1+tid; c2 < 75; c2 += 256){
        u64 a = remv[c2];
        for (int q=0;q<nk;q++) a |= mrow[(size_t)ck[q]*75 + c2];
        remv[c2] = a;
      }
    }
    __syncthreads();
  }
  __syncthreads();
  int kc = s_kc; if (kc > 1000) kc = 1000;
  for (int r = tid; r < 1000; r += 256){
    float v0=0.f,v1=0.f,v2=0.f,v3=0.f,v4=-1e9f;
    if (r < kc){
      int idx = keep[r];
      const double* b = sbox + ((size_t)img*M_CAND + idx)*4;
      v0=(float)b[0]; v1=(float)b[1]; v2=(float)b[2]; v3=(float)b[3];
      v4=(float)ssc[(size_t)img*M_CAND + idx];
    }
    float* o = out + ((size_t)img*1000 + r)*5;
    o[0]=v0; o[1]=v1; o[2]=v2; o[3]=v3; o[4]=v4;
  }
}

// ---------------- host ----------------
extern "C" void kernel_launch(void* const* d_in, const int* in_sizes, int n_in,
                              void* d_out, int out_size, void* d_ws, size_t ws_size,
                              hipStream_t stream)
{
  const float* feat[5];
  for (int i=0;i<5;i++) feat[i] = (const float*)d_in[i];
  const float* cw  = (const float*)d_in[5];
  const float* cb  = (const float*)d_in[6];
  const float* ow  = (const float*)d_in[7];
  const float* ob  = (const float*)d_in[8];
  const float* dwt = (const float*)d_in[9];
  const float* db  = (const float*)d_in[10];
  float* out = (float*)d_out;
  char* ws = (char*)d_ws;
  if (ws_size < WS_NEED) return;

  float*  ascore = (float*)(ws + OFF_ASC);
  u32*    thr    = (u32*)(ws + OFF_THR);
  u32*    quota  = (u32*)(ws + OFF_QUOTA);
  u32*    cnt    = (u32*)(ws + OFF_CNT);
  u32*    sel    = (u32*)(ws + OFF_SEL);
  double* rsc    = (double*)(ws + OFF_RSC);
  double* rdl    = (double*)(ws + OFF_RDL);
  u32*    sord   = (u32*)(ws + OFF_SORD);
  double* cbox   = (double*)(ws + OFF_CBOX);
  double* csc    = (double*)(ws + OFF_CSC);
  u64*    skey   = (u64*)(ws + OFF_SKEY);
  u32*    sidx   = (u32*)(ws + OFF_SIDX);
  double* sbox   = (double*)(ws + OFF_SBOX);
  double* ssc    = (double*)(ws + OFF_SSC);
  u64*    mask   = (u64*)(ws + OFF_MASK);

  k_init<<<27,256,0,stream>>>(cnt, skey, sidx);
  for (int l=0;l<5;l++){
    dim3 g((h_W[l]+31)/32, h_H[l], 2);
    k_conv32<<<g,256,0,stream>>>(feat[l], cw, cb, ow, ob,
                                 ascore + h_SCOFF[l], h_H[l], h_W[l]);
  }
  k_radix32<<<10,1024,0,stream>>>(ascore, thr, quota);
  k_compact32<<<dim3(713,10),256,0,stream>>>(ascore, thr, quota, cnt, sel);
  k_recompute<<<dim3(128,10),256,0,stream>>>(feat[0],feat[1],feat[2],feat[3],feat[4],
                                             cw, cb, ow, ob, dwt, db, sel, cnt, rsc, rdl);
  k_sort1024<<<10,256,0,stream>>>(rsc, cnt, sord);
  k_decode<<<dim3(4,10),256,0,stream>>>(rsc, rdl, sel, sord, cbox, csc, skey, sidx, cnt);
  k_sort<<<2,1024,0,stream>>>(skey, sidx);
  k_gather<<<38,256,0,stream>>>(sidx, cbox, csc, sbox, ssc);
  k_iou<<<dim3(75,75,2),256,0,stream>>>(sbox, mask);
  k_nms<<<2,256,0,stream>>>(mask, sbox, ssc, cnt, out);
}

// Round 3
// 2698.472 us; speedup vs baseline: 2.8567x; 2.6212x over previous
//
#include <hip/hip_runtime.h>
#include <math.h>

typedef unsigned int u32;
typedef unsigned long long u64;
typedef __attribute__((ext_vector_type(8))) short bf16x8;
typedef __attribute__((ext_vector_type(4))) float f32x4;

// ---------------- level tables ----------------
__constant__ int c_W[5]   = {304,152,76,38,19};
__constant__ int c_H[5]   = {200,100,50,25,13};
__constant__ int c_STR[5] = {4,8,16,32,64};
__constant__ int c_SZ[5]  = {32,64,128,256,512};
__constant__ int c_S[5]   = {182400,45600,11400,2850,741};   // H*W*A
__constant__ int c_K1[5]  = {1024,1024,1024,1024,741};       // selection size (margin 24)
__constant__ int c_K2[5]  = {1000,1000,1000,1000,741};       // per-level keep
__constant__ u64 c_SCOFF[5] = {0,364800,456000,478800,484500}; // per-level base (x2 images)
__constant__ int c_LOFF[5] = {0,1000,2000,3000,4000};

static const int h_W[5] = {304,152,76,38,19};
static const int h_H[5] = {200,100,50,25,13};
static const size_t h_SCOFF[5] = {0,364800,456000,478800,484500};

// ---------------- workspace layout ----------------
static constexpr size_t alignup(size_t x){ return (x + 255) & ~(size_t)255; }
static constexpr size_t N_SC   = 485982;     // total scores (both images)
static constexpr int    M_CAND = 4741;       // candidates per image
static constexpr size_t OFF_ASC   = 0;                                    // f32[N_SC]
static constexpr size_t OFF_THR   = alignup(OFF_ASC + N_SC*4);            // u32[16]
static constexpr size_t OFF_QUOTA = OFF_THR + 64;                         // u32[16]
static constexpr size_t OFF_CNT   = OFF_QUOTA + 64;                       // u32[64]
static constexpr size_t OFF_SEL   = alignup(OFF_CNT + 256);               // u32[10][1024]
static constexpr size_t OFF_RSC   = alignup(OFF_SEL + 10*1024*4);         // f64[10][1024]
static constexpr size_t OFF_RDL   = alignup(OFF_RSC + 10*1024*8);         // f64[10][1024][4]
static constexpr size_t OFF_SORD  = alignup(OFF_RDL + 10*1024*4*8);       // u32[10][1024]
static constexpr size_t OFF_CBOX  = alignup(OFF_SORD + 10*1024*4);        // f64[2][4741][4]
static constexpr size_t OFF_CSC   = alignup(OFF_CBOX + 2ull*M_CAND*4*8);  // f64[2][4741]
static constexpr size_t OFF_SKEY  = alignup(OFF_CSC + 2ull*M_CAND*8);     // u64[2][8192] packed (score|8191-cp)
static constexpr size_t OFF_SBOX  = alignup(OFF_SKEY + 2ull*8192*8);      // f64[2][4741][4]
static constexpr size_t OFF_SSC   = alignup(OFF_SBOX + 2ull*M_CAND*4*8);  // f64[2][4741]
static constexpr size_t OFF_MASK  = alignup(OFF_SSC + 2ull*M_CAND*8);     // u64[2][4800][75]
static constexpr size_t OFF_WB    = alignup(OFF_MASK + 2ull*4800*75*8);   // bf16[9][8][256][32]
static constexpr size_t WS_NEED   = OFF_WB + 589824ull*2;                 // ~10.3 MB

__device__ __forceinline__ u64 ordkey(double s){
  u64 b = (u64)__double_as_longlong(s);
  return b ^ ((b >> 63) ? 0xFFFFFFFFFFFFFFFFULL : 0x8000000000000000ULL);
}
__device__ __forceinline__ u32 ordkey32(float s){
  u32 b = __float_as_uint(s);
  return b ^ ((b >> 31) ? 0xFFFFFFFFu : 0x80000000u);
}
__device__ __forceinline__ short bf16rne(float f){
  u32 u = __float_as_uint(f);
  u32 r = (u + 0x7FFFu + ((u >> 16) & 1u)) >> 16;
  return (short)r;
}

// ---------------- K0: init counters + sort padding ----------------
__global__ __launch_bounds__(256) void k_init(u32* cnt, u64* skey){
  int t = blockIdx.x*256 + threadIdx.x;
  if (t < 64) cnt[t] = 0;
  const int npad = 8192 - M_CAND;
  if (t < 2*npad){
    int img = t / npad;
    int j = M_CAND + (t - img*npad);
    skey[(size_t)img*8192 + j] = 0ULL;   // sorts after every real entry
  }
}

// ---------------- K0b: pack conv weights to bf16 [tap][chunk][n][ci32] ----------------
__global__ __launch_bounds__(256) void k_prepw(const float* __restrict__ cw, short* __restrict__ wb2){
  int t = blockIdx.x*256 + threadIdx.x;
  if (t >= 9*8*256*32) return;
  int ci = t & 31, n = (t >> 5) & 255, chunk = (t >> 13) & 7, tap = t >> 16;
  int cig = chunk*32 + ci;
  int ky = tap/3, kx = tap - ky*3;
  float v = cw[((size_t)(n*256 + cig)*3 + ky)*3 + kx];
  wb2[t] = bf16rne(v);
}

// ---------------- K1: bf16 MFMA implicit-GEMM conv3x3 + ReLU + obj 1x1 (approx) ----
// block: 512 thr = 8 waves (2 m-halves x 4 n-quadrants); 64-pixel strip at row y.
__global__ __launch_bounds__(512) void k_convb(
    const float* __restrict__ feat, const short* __restrict__ wb2,
    const float* __restrict__ cb, const float* __restrict__ ow,
    const float* __restrict__ ob, float* __restrict__ score_out,
    int H, int W)
{
  __shared__ __align__(16) short Ap[198*136];   // [ry*66+cx][ci(128, pitch136)] bf16 ~52.6KB
  __shared__ __align__(16) short Bt[256*40];    // [n][ci32 pitch40] bf16 = 20KB
  __shared__ float ps[192];                     // [3][64] partial scores
  const int tid = threadIdx.x;
  const int y = blockIdx.y, x0 = blockIdx.x*64, img = blockIdx.z;
  const size_t HW = (size_t)H*W;
  const float* fb = feat + (size_t)img*256*HW;
  for (int e=tid;e<192;e+=512) ps[e]=0.f;

  const int wid = tid>>6, lane = tid&63;
  const int wr = wid>>2, wc = wid&3;
  const int l15 = lane&15, lg = lane>>4;

  f32x4 acc[2][4];
  #pragma unroll
  for(int a=0;a<2;a++)
    #pragma unroll
    for(int b=0;b<4;b++) acc[a][b] = (f32x4){0.f,0.f,0.f,0.f};

  for (int half=0; half<2; half++){
    __syncthreads();
    // stage A: 128 ci x (3 ry x 66 cx); coalesced over cx, bank-safe pitch 136
    for (int e=tid; e<25344; e+=512){
      int ci = e/198, r = e - ci*198;          // r = ry*66+cx
      int ry = r/66, cx = r - ry*66;
      int yy = y + ry - 1, xx = x0 + cx - 1;
      float v = 0.f;
      if (yy>=0 && yy<H && xx>=0 && xx<W)
        v = fb[(size_t)(half*128+ci)*HW + (size_t)yy*W + xx];
      Ap[r*136 + ci] = bf16rne(v);
    }
    for (int tap=0; tap<9; tap++){
      const int kyy = tap/3, kxx = tap - kyy*3;
      for (int c2=0; c2<4; c2++){
        __syncthreads();
        { // stage B tile (16KB contiguous source), pitch-40 LDS
          const short* bs = wb2 + (((tap<<3) + (half<<2) + c2) << 13);
          for (int p=tid; p<1024; p+=512){
            int n = p>>2, seg = p&3;
            *(uint4*)(Bt + n*40 + (seg<<3)) = *(const uint4*)(bs + (n<<5) + (seg<<3));
          }
        }
        __syncthreads();
        const int colb = kyy*66 + wr*32 + l15 + kxx;
        const int cio  = c2*32 + lg*8;
        bf16x8 a0 = *(const bf16x8*)(Ap + colb*136 + cio);
        bf16x8 a1 = *(const bf16x8*)(Ap + (colb+16)*136 + cio);
        #pragma unroll
        for (int nf=0; nf<4; nf++){
          bf16x8 b = *(const bf16x8*)(Bt + (wc*64 + nf*16 + l15)*40 + lg*8);
          acc[0][nf] = __builtin_amdgcn_mfma_f32_16x16x32_bf16(a0, b, acc[0][nf], 0,0,0);
          acc[1][nf] = __builtin_amdgcn_mfma_f32_16x16x32_bf16(a1, b, acc[1][nf], 0,0,0);
        }
      }
    }
  }
  // epilogue: bias + relu + obj 1x1 (fp32), reduce over n
  float p[3][2][4];
  #pragma unroll
  for (int a=0;a<3;a++)
    #pragma unroll
    for(int mf=0;mf<2;mf++)
      #pragma unroll
      for(int r=0;r<4;r++) p[a][mf][r]=0.f;
  #pragma unroll
  for (int nf=0; nf<4; nf++){
    int n = wc*64 + nf*16 + l15;
    float cbn = cb[n];
    float w0 = ow[n], w1 = ow[256+n], w2 = ow[512+n];
    #pragma unroll
    for (int mf=0; mf<2; mf++)
      #pragma unroll
      for (int r=0;r<4;r++){
        float t = acc[mf][nf][r] + cbn;
        t = t>0.f ? t : 0.f;
        p[0][mf][r] += w0*t; p[1][mf][r] += w1*t; p[2][mf][r] += w2*t;
      }
  }
  #pragma unroll
  for (int a=0;a<3;a++)
    #pragma unroll
    for (int mf=0;mf<2;mf++)
      #pragma unroll
      for (int r=0;r<4;r++){
        float v = p[a][mf][r];
        v += __shfl_xor(v, 1); v += __shfl_xor(v, 2);
        v += __shfl_xor(v, 4); v += __shfl_xor(v, 8);
        p[a][mf][r] = v;
      }
  if (l15 == 0){
    #pragma unroll
    for (int a=0;a<3;a++)
      #pragma unroll
      for (int mf=0;mf<2;mf++)
        #pragma unroll
        for (int r=0;r<4;r++)
          atomicAdd(&ps[a*64 + wr*32 + mf*16 + lg*4 + r], p[a][mf][r]);
  }
  __syncthreads();
  float* so = score_out + (size_t)img*HW*3;
  for (int e=tid; e<192; e+=512){
    int a = e>>6, px = e&63;
    int xg = x0 + px;
    if (xg < W) so[((size_t)y*W + xg)*3 + a] = ps[e] + ob[a];
  }
}

// ---------------- K2: per-(level,image) radix-select of K1-th largest fp32 key ----------------
__global__ __launch_bounds__(1024) void k_radix32(const float* __restrict__ ascore,
                                                  u32* __restrict__ thr, u32* __restrict__ quota)
{
  const int u = blockIdx.x, l = u >> 1, img = u & 1;
  const int n = c_S[l], k = c_K1[l];
  const int tid = threadIdx.x;
  if (n <= k){ if (tid==0){ thr[u]=0u; quota[u]=0xFFFFFFFFu; } return; }
  const float* sc = ascore + c_SCOFF[l] + (size_t)img*n;
  __shared__ u32 hist[2048];
  __shared__ u32 grp[32];
  __shared__ u32 s_pref;
  __shared__ u32 s_rem;
  if (tid==0){ s_pref=0u; s_rem=(u32)k; }
  const int shifts[3] = {21,10,0};
  const int bitsA[3]  = {11,11,10};
  for (int p=0;p<3;p++){
    const int nb = 1 << bitsA[p];
    for (int i=tid;i<nb;i+=1024) hist[i]=0u;
    __syncthreads();
    const u32 pref = s_pref;
    const int sh = shifts[p], hb = bitsA[p];
    for (int i=tid;i<n;i+=1024){
      u32 key = ordkey32(sc[i]);
      bool m = (p==0) || ((key >> (sh+hb)) == pref);
      if (m) atomicAdd(&hist[(key>>sh) & (u32)(nb-1)], 1u);
    }
    __syncthreads();
    const int per = nb >> 5;
    if (tid < 32){ u32 s=0; for (int q=0;q<per;q++) s += hist[tid*per+q]; grp[tid]=s; }
    __syncthreads();
    if (tid==0){
      u32 rem = s_rem, cum = 0;
      int g = 31;
      for (; g>0; g--){ if (cum + grp[g] >= rem) break; cum += grp[g]; }
      int b = (g+1)*per - 1;
      for (; b > g*per; b--){ if (cum + hist[b] >= rem) break; cum += hist[b]; }
      s_pref = (s_pref << hb) | (u32)b;
      s_rem = rem - cum;
    }
    __syncthreads();
  }
  if (tid==0){ thr[u] = s_pref; quota[u] = s_rem; }
}

// ---------------- K2b: compact selected indices ----------------
__global__ __launch_bounds__(256) void k_compact32(const float* __restrict__ ascore,
    const u32* __restrict__ thr, const u32* __restrict__ quota,
    u32* __restrict__ cnt, u32* __restrict__ sel)
{
  const int u = blockIdx.y, l = u >> 1, img = u & 1;
  const int n = c_S[l];
  const int i = blockIdx.x*256 + threadIdx.x;
  if (i >= n) return;
  const float* sc = ascore + c_SCOFF[l] + (size_t)img*n;
  u32 key = ordkey32(sc[i]);
  u32 q = quota[u];
  bool take = false;
  if (q == 0xFFFFFFFFu) take = true;           // n <= k: take all
  else {
    u32 t = thr[u];
    if (key > t) take = true;
    else if (key == t){ if (atomicAdd(&cnt[16+u],1u) < q) take = true; }
  }
  if (take){ u32 p = atomicAdd(&cnt[u],1u); if (p < 1024u) sel[u*1024 + p] = (u32)i; }
}

// ---------------- K3: fp64 recompute of t + obj + deltas at selected positions ----------------
__global__ __launch_bounds__(256) void k_recompute(
    const float* __restrict__ f2, const float* __restrict__ f3,
    const float* __restrict__ f4, const float* __restrict__ f5,
    const float* __restrict__ f6,
    const float* __restrict__ cw, const float* __restrict__ cb,
    const float* __restrict__ ow, const float* __restrict__ ob,
    const float* __restrict__ dwt, const float* __restrict__ db,
    const u32* __restrict__ sel, const u32* __restrict__ cnt,
    double* __restrict__ rsc, double* __restrict__ rdl)
{
  const int u = blockIdx.y, l = u >> 1, img = u & 1;
  const int j0 = blockIdx.x * 8;
  const int cu = (int)cnt[u];
  if (j0 >= cu) return;
  const int W = c_W[l], H = c_H[l];
  const size_t HW = (size_t)W*H;
  const float* fl = (l==0)?f2:(l==1)?f3:(l==2)?f4:(l==3)?f5:f6;
  const float* fb = fl + (size_t)img*256*HW;
  __shared__ float  sp[8*576];
  __shared__ double tl2[8][257];
  __shared__ int sx[8], sy[8], sa[8], sv[8];
  const int tid = threadIdx.x;
  if (tid < 8){
    int j = j0 + tid; int ok = (j < cu) ? 1 : 0;
    u32 i = ok ? sel[u*1024 + j] : 0u;
    int pos = (int)(i/3u);
    sa[tid] = (int)i - pos*3; sx[tid] = pos % W; sy[tid] = pos / W; sv[tid] = ok;
  }
  double acc[8];
  #pragma unroll
  for (int e=0;e<8;e++) acc[e]=0.0;
  __syncthreads();
  for (int ci0=0; ci0<256; ci0+=64){
    for (int el=tid; el<4608; el+=256){
      int e = el/576, r = el - e*576;
      int ci = r/9, q = r - ci*9, ky = q/3, kx = q - ky*3;
      int yy = sy[e]+ky-1, xx = sx[e]+kx-1;
      float v = 0.0f;
      if (yy>=0 && yy<H && xx>=0 && xx<W) v = fb[(size_t)(ci0+ci)*HW + (size_t)yy*W + xx];
      sp[el] = v;
    }
    __syncthreads();
    const float* wq = cw + (size_t)tid*2304 + (size_t)ci0*9;
    for (int kk=0; kk<576; kk+=4){
      float4 w4 = *(const float4*)(wq + kk);
      #pragma unroll
      for (int e=0;e<8;e++){
        float4 p4 = *(const float4*)(sp + e*576 + kk);
        acc[e] += (double)w4.x*(double)p4.x;
        acc[e] += (double)w4.y*(double)p4.y;
        acc[e] += (double)w4.z*(double)p4.z;
        acc[e] += (double)w4.w*(double)p4.w;
      }
    }
    __syncthreads();
  }
  {
    double bc = (double)cb[tid];
    #pragma unroll
    for (int e=0;e<8;e++){ double t = acc[e] + bc; tl2[e][tid] = t > 0.0 ? t : 0.0; }
  }
  __syncthreads();
  if (tid < 40){
    int e = tid/5, q = tid - e*5;
    if (sv[e]){
      int a = sa[e];
      const float* wv = (q==0) ? (ow + a*256) : (dwt + (size_t)(a*4 + q-1)*256);
      double bias = (q==0) ? (double)ob[a] : (double)db[a*4 + q-1];
      double s = 0.0;
      for (int c=0;c<256;c++) s += (double)wv[c]*tl2[e][c];
      s += bias;
      int j = j0 + e;
      if (q==0) rsc[(size_t)u*1024 + j] = s;
      else      rdl[((size_t)u*1024 + j)*4 + (q-1)] = s;
    }
  }
}

// ---------------- K3b: per-(level,image) bitonic sort of 1024 by exact fp64 score ----------------
__global__ __launch_bounds__(256) void k_sort1024(const double* __restrict__ rsc,
    const u32* __restrict__ cnt, u32* __restrict__ sord)
{
  const int u = blockIdx.x;
  const int cu = (int)cnt[u];
  const int tid = threadIdx.x;
  __shared__ u64 kk[1024];
  __shared__ u32 pp[1024];
  for (int i=tid;i<1024;i+=256){
    if (i < cu){ kk[i] = ordkey(rsc[(size_t)u*1024 + i]); pp[i] = (u32)i; }
    else       { kk[i] = 0ULL; pp[i] = 0xFFFFFFFFu; }
  }
  __syncthreads();
  for (int k=2;k<=1024;k<<=1){
    for (int j=k>>1;j>0;j>>=1){
      for (int i=tid;i<1024;i+=256){
        int l2 = i ^ j;
        if (l2 > i){
          u64 ka = kk[i], kb = kk[l2];
          u32 ia = pp[i], ib = pp[l2];
          bool before = (ka > kb) || (ka == kb && ia < ib);
          bool up = (i & k) == 0;
          if (up ? !before : before){
            kk[i]=kb; kk[l2]=ka; pp[i]=ib; pp[l2]=ia;
          }
        }
      }
      __syncthreads();
    }
  }
  for (int i=tid;i<1024;i+=256) sord[(size_t)u*1024 + i] = pp[i];
}

// ---------------- K4: decode boxes (exact mixed fp32/fp64 like reference) ----------------
__global__ __launch_bounds__(256) void k_decode(
    const double* __restrict__ rsc, const double* __restrict__ rdl,
    const u32* __restrict__ sel, const u32* __restrict__ sord,
    double* __restrict__ cbox, double* __restrict__ csc,
    u64* __restrict__ skey, u32* __restrict__ cnt)
{
#pragma clang fp contract(off)
  const int u = blockIdx.y, l = u >> 1, img = u & 1;
  const int slot = blockIdx.x*256 + threadIdx.x;
  if (slot >= c_K2[l]) return;
  const u32 entry = sord[(size_t)u*1024 + slot];
  const u32 idx = sel[u*1024 + entry];
  const double s = rsc[(size_t)u*1024 + entry];
  const double d0 = rdl[((size_t)u*1024+entry)*4+0], d1 = rdl[((size_t)u*1024+entry)*4+1];
  double d2 = rdl[((size_t)u*1024+entry)*4+2], d3 = rdl[((size_t)u*1024+entry)*4+3];
  const int pos = (int)(idx/3u), a = (int)idx - pos*3;
  const int W = c_W[l];
  const int x = pos % W, y = pos / W;
  const double rr = (a==0) ? 0.5 : ((a==1) ? 1.0 : 2.0);
  const double sz = (double)c_SZ[l];
  const double wa = sqrt(sz*sz/rr);
  const double ha = wa*rr;
  const float xs = (float)(x*c_STR[l]);
  const float ys = (float)(y*c_STR[l]);
  const float ax0 = xs + (float)(-0.5*wa);
  const float ax1 = xs + (float)( 0.5*wa);
  const float ay0 = ys + (float)(-0.5*ha);
  const float ay1 = ys + (float)( 0.5*ha);
  const float wf = ax1 - ax0;
  const float hf = ay1 - ay0;
  const float cxf = ax0 + 0.5f*wf;
  const float cyf = ay0 + 0.5f*hf;
  const double Wd = (double)wf, Hd = (double)hf, CX = (double)cxf, CY = (double)cyf;
  const double SCLAMP = 4.135166556742356;   // log(1000/16)
  if (d2 > SCLAMP) d2 = SCLAMP;
  if (d3 > SCLAMP) d3 = SCLAMP;
  double pcx = d0*Wd; pcx = pcx + CX;
  double pcy = d1*Hd; pcy = pcy + CY;
  const double pw = exp(d2)*Wd;
  const double ph = exp(d3)*Hd;
  double x0 = pcx - 0.5*pw;
  double y0 = pcy - 0.5*ph;
  double x1 = pcx + 0.5*pw;
  double y1 = pcy + 0.5*ph;
  x0 = fmin(fmax(x0, 0.0), 1216.0);
  x1 = fmin(fmax(x1, 0.0), 1216.0);
  y0 = fmin(fmax(y0, 0.0), 800.0);
  y1 = fmin(fmax(y1, 0.0), 800.0);
  const bool valid = (x1 - x0 > 0.0) && (y1 - y0 > 0.0);
  const double sm = valid ? s : -1e9;
  const int cp = c_LOFF[l] + slot;
  double* cb = cbox + ((size_t)img*M_CAND + cp)*4;
  cb[0]=x0; cb[1]=y0; cb[2]=x1; cb[3]=y1;
  csc[(size_t)img*M_CAND + cp] = sm;
  // packed key: truncated fp64 ordkey (13 low mantissa bits dropped; resolution
  // ~2e-12 rel << 1e-4 score gaps) | (8191-cp) => sort desc == (score desc, cp asc)
  skey[(size_t)img*8192 + cp] = (ordkey(sm) & ~(u64)0x1FFF) | (u64)(8191 - cp);
  if (valid) atomicAdd(&cnt[32+img], 1u);
}

// ---------------- K5: per-image bitonic sort of packed keys, fully in LDS ----------------
__global__ __launch_bounds__(1024) void k_sort(u64* __restrict__ key)
{
  const int img = blockIdx.x;
  u64* g = key + (size_t)img*8192;
  __shared__ u64 kk[8192];   // 64KB
  const int tid = threadIdx.x;
  for (int i=tid;i<8192;i+=1024) kk[i]=g[i];
  __syncthreads();
  for (int k=2;k<=8192;k<<=1){
    for (int j=k>>1;j>0;j>>=1){
      for (int i=tid;i<8192;i+=1024){
        int l = i ^ j;
        if (l > i){
          u64 ka = kk[i], kb = kk[l];
          bool before = (ka > kb);
          bool up = (i & k) == 0;
          if (up ? !before : before){ kk[i]=kb; kk[l]=ka; }
        }
      }
      __syncthreads();
    }
  }
  for (int i=tid;i<8192;i+=1024) g[i]=kk[i];
}

// ---------------- K5b: gather sorted boxes/scores ----------------
__global__ __launch_bounds__(256) void k_gather(const u64* __restrict__ skey,
    const double* __restrict__ cbox, const double* __restrict__ csc,
    double* __restrict__ sbox, double* __restrict__ ssc)
{
  int t = blockIdx.x*256 + threadIdx.x;
  if (t >= 2*M_CAND) return;
  int img = t / M_CAND, j = t - img*M_CAND;
  u32 b = 8191u - (u32)(skey[(size_t)img*8192 + j] & 0x1FFFull);
  const double* cb = cbox + ((size_t)img*M_CAND + b)*4;
  double* sb = sbox + ((size_t)img*M_CAND + j)*4;
  sb[0]=cb[0]; sb[1]=cb[1]; sb[2]=cb[2]; sb[3]=cb[3];
  ssc[(size_t)img*M_CAND + j] = csc[(size_t)img*M_CAND + b];
}

// ---------------- K6: pairwise IoU suppression bitmask ----------------
__global__ __launch_bounds__(256) void k_iou(const double* __restrict__ sbox, u64* __restrict__ mask)
{
#pragma clang fp contract(off)
  const int jb = blockIdx.x, ib = blockIdx.y, img = blockIdx.z;
  if (jb < ib) return;
  __shared__ double ibx[64][4];
  const int tid = threadIdx.x;
  const int lane = tid & 63, wv = tid >> 6;
  if (tid < 64){
    int ig = ib*64 + tid;
    if (ig < M_CAND){
      const double* b = sbox + ((size_t)img*M_CAND + ig)*4;
      ibx[tid][0]=b[0]; ibx[tid][1]=b[1]; ibx[tid][2]=b[2]; ibx[tid][3]=b[3];
    } else { ibx[tid][0]=0; ibx[tid][1]=0; ibx[tid][2]=0; ibx[tid][3]=0; }
  }
  const int jg = jb*64 + lane;
  double jx0=0,jy0=0,jx1=0,jy1=0;
  if (jg < M_CAND){
    const double* b = sbox + ((size_t)img*M_CAND + jg)*4;
    jx0=b[0]; jy0=b[1]; jx1=b[2]; jy1=b[3];
  }
  const double ja = (jx1-jx0)*(jy1-jy0);
  __syncthreads();
  for (int s=0;s<16;s++){
    const int il = wv*16 + s;
    const int ig = ib*64 + il;
    double bx0=ibx[il][0], by0=ibx[il][1], bx1=ibx[il][2], by1=ibx[il][3];
    double lt0 = bx0 > jx0 ? bx0 : jx0;
    double lt1 = by0 > jy0 ? by0 : jy0;
    double rb0 = bx1 < jx1 ? bx1 : jx1;
    double rb1 = by1 < jy1 ? by1 : jy1;
    double w = rb0-lt0; if (w<0.0) w=0.0;
    double h = rb1-lt1; if (h<0.0) h=0.0;
    double inter = w*h;
    double ia = (bx1-bx0)*(by1-by0);
    double un = ia + ja - inter; if (un < 1e-9) un = 1e-9;
    bool bit = (jg > ig) && (jg < M_CAND) && (inter/un > 0.7);
    u64 m = __ballot(bit);
    if (lane == 0) mask[((size_t)img*4800 + ig)*75 + jb] = m;
  }
}

// ---------------- K7: chunked greedy scan + output ----------------
__global__ __launch_bounds__(256) void k_nms(const u64* __restrict__ mask,
    const double* __restrict__ sbox, const double* __restrict__ ssc,
    const u32* __restrict__ cnt, float* __restrict__ out)
{
  const int img = blockIdx.x;
  const int tid = threadIdx.x;
  __shared__ u64 remv[75];
  __shared__ u64 diag[64];
  __shared__ int keep[1000];
  __shared__ int ck[64];
  __shared__ int s_kc, s_nk, s_done;
  if (tid < 75) remv[tid] = 0ULL;
  if (tid == 0){ s_kc = 0; s_done = 0; }
  int vc = (int)cnt[32+img]; if (vc > M_CAND) vc = M_CAND;
  const u64* mrow = mask + (size_t)img*4800*75;
  __syncthreads();
  for (int c=0; c<75; c++){
    if (c*64 >= vc) break;
    if (tid < 64) diag[tid] = mrow[(size_t)(c*64+tid)*75 + c];
    __syncthreads();
    if (tid == 0){
      u64 w = remv[c];
      int kc = s_kc, nk = 0;
      int lim = vc - c*64; if (lim > 64) lim = 64;
      for (int k=0;k<lim;k++){
        if (!((w >> k) & 1ULL)){
          int idx = c*64 + k;
          keep[kc] = idx;
          ck[nk++] = idx;
          kc++;
          if (kc >= 1000) break;
          w |= diag[k];
        }
      }
      s_kc = kc; s_nk = nk;
      if (kc >= 1000) s_done = 1;
    }
    __syncthreads();
    if (s_done) break;
    const int nk = s_nk;
    if (nk > 0){
      for (int c2 = c+1+tid; c2 < 75; c2 += 256){
        u64 a = remv[c2];
        for (int q=0;q<nk;q++) a |= mrow[(size_t)ck[q]*75 + c2];
        remv[c2] = a;
      }
    }
    __syncthreads();
  }
  __syncthreads();
  int kc = s_kc; if (kc > 1000) kc = 1000;
  for (int r = tid; r < 1000; r += 256){
    float v0=0.f,v1=0.f,v2=0.f,v3=0.f,v4=-1e9f;
    if (r < kc){
      int idx = keep[r];
      const double* b = sbox + ((size_t)img*M_CAND + idx)*4;
      v0=(float)b[0]; v1=(float)b[1]; v2=(float)b[2]; v3=(float)b[3];
      v4=(float)ssc[(size_t)img*M_CAND + idx];
    }
    float* o = out + ((size_t)img*1000 + r)*5;
    o[0]=v0; o[1]=v1; o[2]=v2; o[3]=v3; o[4]=v4;
  }
}

// ---------------- host ----------------
extern "C" void kernel_launch(void* const* d_in, const int* in_sizes, int n_in,
                              void* d_out, int out_size, void* d_ws, size_t ws_size,
                              hipStream_t stream)
{
  const float* feat[5];
  for (int i=0;i<5;i++) feat[i] = (const float*)d_in[i];
  const float* cw  = (const float*)d_in[5];
  const float* cb  = (const float*)d_in[6];
  const float* ow  = (const float*)d_in[7];
  const float* ob  = (const float*)d_in[8];
  const float* dwt = (const float*)d_in[9];
  const float* db  = (const float*)d_in[10];
  float* out = (float*)d_out;
  char* ws = (char*)d_ws;
  if (ws_size < WS_NEED) return;

  float*  ascore = (float*)(ws + OFF_ASC);
  u32*    thr    = (u32*)(ws + OFF_THR);
  u32*    quota  = (u32*)(ws + OFF_QUOTA);
  u32*    cnt    = (u32*)(ws + OFF_CNT);
  u32*    sel    = (u32*)(ws + OFF_SEL);
  double* rsc    = (double*)(ws + OFF_RSC);
  double* rdl    = (double*)(ws + OFF_RDL);
  u32*    sord   = (u32*)(ws + OFF_SORD);
  double* cbox   = (double*)(ws + OFF_CBOX);
  double* csc    = (double*)(ws + OFF_CSC);
  u64*    skey   = (u64*)(ws + OFF_SKEY);
  double* sbox   = (double*)(ws + OFF_SBOX);
  double* ssc    = (double*)(ws + OFF_SSC);
  u64*    mask   = (u64*)(ws + OFF_MASK);
  short*  wb2    = (short*)(ws + OFF_WB);

  k_prepw<<<2304,256,0,stream>>>(cw, wb2);
  k_init<<<27,256,0,stream>>>(cnt, skey);
  for (int l=0;l<5;l++){
    dim3 g((h_W[l]+63)/64, h_H[l], 2);
    k_convb<<<g,512,0,stream>>>(feat[l], wb2, cb, ow, ob,
                                ascore + h_SCOFF[l], h_H[l], h_W[l]);
  }
  k_radix32<<<10,1024,0,stream>>>(ascore, thr, quota);
  k_compact32<<<dim3(713,10),256,0,stream>>>(ascore, thr, quota, cnt, sel);
  k_recompute<<<dim3(128,10),256,0,stream>>>(feat[0],feat[1],feat[2],feat[3],feat[4],
                                             cw, cb, ow, ob, dwt, db, sel, cnt, rsc, rdl);
  k_sort1024<<<10,256,0,stream>>>(rsc, cnt, sord);
  k_decode<<<dim3(4,10),256,0,stream>>>(rsc, rdl, sel, sord, cbox, csc, skey, cnt);
  k_sort<<<2,1024,0,stream>>>(skey);
  k_gather<<<38,256,0,stream>>>(skey, cbox, csc, sbox, ssc);
  k_iou<<<dim3(75,75,2),256,0,stream>>>(sbox, mask);
  k_nms<<<2,256,0,stream>>>(mask, sbox, ssc, cnt, out);
}

// Round 4
// 2362.538 us; speedup vs baseline: 3.2629x; 1.1422x over previous
//
#include <hip/hip_runtime.h>
#include <math.h>

typedef unsigned int u32;
typedef unsigned long long u64;
typedef __attribute__((ext_vector_type(8))) short bf16x8;
typedef __attribute__((ext_vector_type(4))) float f32x4;

// ---------------- level tables ----------------
__constant__ int c_W[5]   = {304,152,76,38,19};
__constant__ int c_H[5]   = {200,100,50,25,13};
__constant__ int c_STR[5] = {4,8,16,32,64};
__constant__ int c_SZ[5]  = {32,64,128,256,512};
__constant__ int c_S[5]   = {182400,45600,11400,2850,741};   // H*W*A
__constant__ int c_K1[5]  = {1024,1024,1024,1024,741};       // selection size (margin 24)
__constant__ int c_K2[5]  = {1000,1000,1000,1000,741};       // per-level keep
__constant__ u64 c_SCOFF[5] = {0,364800,456000,478800,484500}; // per-level base (x2 images)
__constant__ int c_LOFF[5] = {0,1000,2000,3000,4000};

static const int h_W[5] = {304,152,76,38,19};
static const int h_H[5] = {200,100,50,25,13};
static const size_t h_SCOFF[5] = {0,364800,456000,478800,484500};

// ---------------- workspace layout ----------------
static constexpr size_t alignup(size_t x){ return (x + 255) & ~(size_t)255; }
static constexpr size_t N_SC   = 485982;     // total scores (both images)
static constexpr int    M_CAND = 4741;       // candidates per image
static constexpr size_t OFF_ASC   = 0;                                    // f32[N_SC]
static constexpr size_t OFF_THR   = alignup(OFF_ASC + N_SC*4);            // u32[16]
static constexpr size_t OFF_QUOTA = OFF_THR + 64;                         // u32[16]
static constexpr size_t OFF_CNT   = OFF_QUOTA + 64;                       // u32[64]
static constexpr size_t OFF_SEL   = alignup(OFF_CNT + 256);               // u32[10][1024]
static constexpr size_t OFF_RSC   = alignup(OFF_SEL + 10*1024*4);         // f64[10][1024]
static constexpr size_t OFF_RDL   = alignup(OFF_RSC + 10*1024*8);         // f64[10][1024][4]
static constexpr size_t OFF_SORD  = alignup(OFF_RDL + 10*1024*4*8);       // u32[10][1024]
static constexpr size_t OFF_CBOX  = alignup(OFF_SORD + 10*1024*4);        // f64[2][4741][4]
static constexpr size_t OFF_CSC   = alignup(OFF_CBOX + 2ull*M_CAND*4*8);  // f64[2][4741]
static constexpr size_t OFF_SKEY  = alignup(OFF_CSC + 2ull*M_CAND*8);     // u64[2][8192] packed (score|8191-cp)
static constexpr size_t OFF_SBOX  = alignup(OFF_SKEY + 2ull*8192*8);      // f64[2][4741][4]
static constexpr size_t OFF_SSC   = alignup(OFF_SBOX + 2ull*M_CAND*4*8);  // f64[2][4741]
static constexpr size_t OFF_MASK  = alignup(OFF_SSC + 2ull*M_CAND*8);     // u64[2][4800][75]
static constexpr size_t OFF_WB    = alignup(OFF_MASK + 2ull*4800*75*8);   // bf16[9][8][256][32]
static constexpr size_t OFF_WT    = alignup(OFF_WB + 589824ull*2);        // f32[2304][256] transposed conv w
static constexpr size_t WS_NEED   = OFF_WT + 589824ull*4;                 // ~12.7 MB

__device__ __forceinline__ u64 ordkey(double s){
  u64 b = (u64)__double_as_longlong(s);
  return b ^ ((b >> 63) ? 0xFFFFFFFFFFFFFFFFULL : 0x8000000000000000ULL);
}
__device__ __forceinline__ u32 ordkey32(float s){
  u32 b = __float_as_uint(s);
  return b ^ ((b >> 31) ? 0xFFFFFFFFu : 0x80000000u);
}
__device__ __forceinline__ short bf16rne(float f){
  u32 u = __float_as_uint(f);
  u32 r = (u + 0x7FFFu + ((u >> 16) & 1u)) >> 16;
  return (short)r;
}

// ---------------- K0: prep — counters, sort padding, bf16 weight pack, fp32 weight transpose ----
__global__ __launch_bounds__(256) void k_prep(const float* __restrict__ cw,
                                              short* __restrict__ wb2, float* __restrict__ wT,
                                              u32* cnt, u64* skey){
  int t = blockIdx.x*256 + threadIdx.x;   // grid = 2304*256 = 589824 exactly
  if (t < 64) cnt[t] = 0;
  const int npad = 8192 - M_CAND;
  if (t < 2*npad){
    int img = t / npad;
    int j = M_CAND + (t - img*npad);
    skey[(size_t)img*8192 + j] = 0ULL;   // sorts after every real entry
  }
  // bf16 MFMA pack: [tap][chunk][n][ci32]
  {
    int ci = t & 31, n = (t >> 5) & 255, chunk = (t >> 13) & 7, tap = t >> 16;
    int cig = chunk*32 + ci;
    int ky = tap/3, kx = tap - ky*3;
    wb2[t] = bf16rne(cw[((size_t)(n*256 + cig)*3 + ky)*3 + kx]);
  }
  // fp32 transpose for recompute: wT[k*256+co] = cw[co*2304+k]
  {
    int k = t >> 8, co = t & 255;
    wT[t] = cw[(size_t)co*2304 + k];
  }
}

// ---------------- K1: bf16 MFMA implicit-GEMM conv3x3 + ReLU + obj 1x1 (approx) ----
// block: 512 thr = 8 waves (2 m-halves x 4 n-quadrants); 64-pixel strip at row y.
__global__ __launch_bounds__(512) void k_convb(
    const float* __restrict__ feat, const short* __restrict__ wb2,
    const float* __restrict__ cb, const float* __restrict__ ow,
    const float* __restrict__ ob, float* __restrict__ score_out,
    int H, int W)
{
  __shared__ __align__(16) short Ap[198*136];   // [ry*66+cx][ci(128, pitch136)] bf16 ~52.6KB
  __shared__ __align__(16) short Bt[256*40];    // [n][ci32 pitch40] bf16 = 20KB
  __shared__ float ps[192];                     // [3][64] partial scores
  const int tid = threadIdx.x;
  const int y = blockIdx.y, x0 = blockIdx.x*64, img = blockIdx.z;
  const size_t HW = (size_t)H*W;
  const float* fb = feat + (size_t)img*256*HW;
  for (int e=tid;e<192;e+=512) ps[e]=0.f;

  const int wid = tid>>6, lane = tid&63;
  const int wr = wid>>2, wc = wid&3;
  const int l15 = lane&15, lg = lane>>4;

  f32x4 acc[2][4];
  #pragma unroll
  for(int a=0;a<2;a++)
    #pragma unroll
    for(int b=0;b<4;b++) acc[a][b] = (f32x4){0.f,0.f,0.f,0.f};

  for (int half=0; half<2; half++){
    __syncthreads();
    // stage A: 128 ci x (3 ry x 66 cx); coalesced over cx, bank-safe pitch 136
    for (int e=tid; e<25344; e+=512){
      int ci = e/198, r = e - ci*198;          // r = ry*66+cx
      int ry = r/66, cx = r - ry*66;
      int yy = y + ry - 1, xx = x0 + cx - 1;
      float v = 0.f;
      if (yy>=0 && yy<H && xx>=0 && xx<W)
        v = fb[(size_t)(half*128+ci)*HW + (size_t)yy*W + xx];
      Ap[r*136 + ci] = bf16rne(v);
    }
    for (int tap=0; tap<9; tap++){
      const int kyy = tap/3, kxx = tap - kyy*3;
      for (int c2=0; c2<4; c2++){
        __syncthreads();
        { // stage B tile (16KB contiguous source), pitch-40 LDS
          const short* bs = wb2 + (((tap<<3) + (half<<2) + c2) << 13);
          for (int p=tid; p<1024; p+=512){
            int n = p>>2, seg = p&3;
            *(uint4*)(Bt + n*40 + (seg<<3)) = *(const uint4*)(bs + (n<<5) + (seg<<3));
          }
        }
        __syncthreads();
        const int colb = kyy*66 + wr*32 + l15 + kxx;
        const int cio  = c2*32 + lg*8;
        bf16x8 a0 = *(const bf16x8*)(Ap + colb*136 + cio);
        bf16x8 a1 = *(const bf16x8*)(Ap + (colb+16)*136 + cio);
        #pragma unroll
        for (int nf=0; nf<4; nf++){
          bf16x8 b = *(const bf16x8*)(Bt + (wc*64 + nf*16 + l15)*40 + lg*8);
          acc[0][nf] = __builtin_amdgcn_mfma_f32_16x16x32_bf16(a0, b, acc[0][nf], 0,0,0);
          acc[1][nf] = __builtin_amdgcn_mfma_f32_16x16x32_bf16(a1, b, acc[1][nf], 0,0,0);
        }
      }
    }
  }
  // epilogue: bias + relu + obj 1x1 (fp32), reduce over n
  float p[3][2][4];
  #pragma unroll
  for (int a=0;a<3;a++)
    #pragma unroll
    for(int mf=0;mf<2;mf++)
      #pragma unroll
      for(int r=0;r<4;r++) p[a][mf][r]=0.f;
  #pragma unroll
  for (int nf=0; nf<4; nf++){
    int n = wc*64 + nf*16 + l15;
    float cbn = cb[n];
    float w0 = ow[n], w1 = ow[256+n], w2 = ow[512+n];
    #pragma unroll
    for (int mf=0; mf<2; mf++)
      #pragma unroll
      for (int r=0;r<4;r++){
        float t = acc[mf][nf][r] + cbn;
        t = t>0.f ? t : 0.f;
        p[0][mf][r] += w0*t; p[1][mf][r] += w1*t; p[2][mf][r] += w2*t;
      }
  }
  #pragma unroll
  for (int a=0;a<3;a++)
    #pragma unroll
    for (int mf=0;mf<2;mf++)
      #pragma unroll
      for (int r=0;r<4;r++){
        float v = p[a][mf][r];
        v += __shfl_xor(v, 1); v += __shfl_xor(v, 2);
        v += __shfl_xor(v, 4); v += __shfl_xor(v, 8);
        p[a][mf][r] = v;
      }
  if (l15 == 0){
    #pragma unroll
    for (int a=0;a<3;a++)
      #pragma unroll
      for (int mf=0;mf<2;mf++)
        #pragma unroll
        for (int r=0;r<4;r++)
          atomicAdd(&ps[a*64 + wr*32 + mf*16 + lg*4 + r], p[a][mf][r]);
  }
  __syncthreads();
  float* so = score_out + (size_t)img*HW*3;
  for (int e=tid; e<192; e+=512){
    int a = e>>6, px = e&63;
    int xg = x0 + px;
    if (xg < W) so[((size_t)y*W + xg)*3 + a] = ps[e] + ob[a];
  }
}

// ---------------- K2: per-(level,image) radix-select of K1-th largest fp32 key ----------------
__global__ __launch_bounds__(1024) void k_radix32(const float* __restrict__ ascore,
                                                  u32* __restrict__ thr, u32* __restrict__ quota)
{
  const int u = blockIdx.x, l = u >> 1, img = u & 1;
  const int n = c_S[l], k = c_K1[l];
  const int tid = threadIdx.x;
  if (n <= k){ if (tid==0){ thr[u]=0u; quota[u]=0xFFFFFFFFu; } return; }
  const float* sc = ascore + c_SCOFF[l] + (size_t)img*n;
  __shared__ u32 hist[2048];
  __shared__ u32 grp[32];
  __shared__ u32 s_pref;
  __shared__ u32 s_rem;
  if (tid==0){ s_pref=0u; s_rem=(u32)k; }
  const int shifts[3] = {21,10,0};
  const int bitsA[3]  = {11,11,10};
  for (int p=0;p<3;p++){
    const int nb = 1 << bitsA[p];
    for (int i=tid;i<nb;i+=1024) hist[i]=0u;
    __syncthreads();
    const u32 pref = s_pref;
    const int sh = shifts[p], hb = bitsA[p];
    for (int i=tid;i<n;i+=1024){
      u32 key = ordkey32(sc[i]);
      bool m = (p==0) || ((key >> (sh+hb)) == pref);
      if (m) atomicAdd(&hist[(key>>sh) & (u32)(nb-1)], 1u);
    }
    __syncthreads();
    const int per = nb >> 5;
    if (tid < 32){ u32 s=0; for (int q=0;q<per;q++) s += hist[tid*per+q]; grp[tid]=s; }
    __syncthreads();
    if (tid==0){
      u32 rem = s_rem, cum = 0;
      int g = 31;
      for (; g>0; g--){ if (cum + grp[g] >= rem) break; cum += grp[g]; }
      int b = (g+1)*per - 1;
      for (; b > g*per; b--){ if (cum + hist[b] >= rem) break; cum += hist[b]; }
      s_pref = (s_pref << hb) | (u32)b;
      s_rem = rem - cum;
    }
    __syncthreads();
  }
  if (tid==0){ thr[u] = s_pref; quota[u] = s_rem; }
}

// ---------------- K2b: compact selected indices ----------------
__global__ __launch_bounds__(256) void k_compact32(const float* __restrict__ ascore,
    const u32* __restrict__ thr, const u32* __restrict__ quota,
    u32* __restrict__ cnt, u32* __restrict__ sel)
{
  const int u = blockIdx.y, l = u >> 1, img = u & 1;
  const int n = c_S[l];
  const int i = blockIdx.x*256 + threadIdx.x;
  if (i >= n) return;
  const float* sc = ascore + c_SCOFF[l] + (size_t)img*n;
  u32 key = ordkey32(sc[i]);
  u32 q = quota[u];
  bool take = false;
  if (q == 0xFFFFFFFFu) take = true;           // n <= k: take all
  else {
    u32 t = thr[u];
    if (key > t) take = true;
    else if (key == t){ if (atomicAdd(&cnt[16+u],1u) < q) take = true; }
  }
  if (take){ u32 p = atomicAdd(&cnt[u],1u); if (p < 1024u) sel[u*1024 + p] = (u32)i; }
}

// ---------------- K3: fp64 recompute of t + obj + deltas at selected positions ----------------
// block = 8 entries; 256 threads = intermediate channel co.
// Patch staged in LDS as DOUBLE (cvt once); weights read coalesced from transposed wT.
__global__ __launch_bounds__(256) void k_recompute(
    const float* __restrict__ f2, const float* __restrict__ f3,
    const float* __restrict__ f4, const float* __restrict__ f5,
    const float* __restrict__ f6,
    const float* __restrict__ wT, const float* __restrict__ cb,
    const float* __restrict__ ow, const float* __restrict__ ob,
    const float* __restrict__ dwt, const float* __restrict__ db,
    const u32* __restrict__ sel, const u32* __restrict__ cnt,
    double* __restrict__ rsc, double* __restrict__ rdl)
{
  const int u = blockIdx.y, l = u >> 1, img = u & 1;
  const int j0 = blockIdx.x * 8;
  const int cu = (int)cnt[u];
  if (j0 >= cu) return;
  const int W = c_W[l], H = c_H[l];
  const size_t HW = (size_t)W*H;
  const float* fl = (l==0)?f2:(l==1)?f3:(l==2)?f4:(l==3)?f5:f6;
  const float* fb = fl + (size_t)img*256*HW;
  __shared__ double spd[4608];       // 36.9 KB: [8 entries][576] doubles; aliased as tl2 after loop
  __shared__ int sx[8], sy[8], sa[8], sv[8];
  const int tid = threadIdx.x;
  if (tid < 8){
    int j = j0 + tid; int ok = (j < cu) ? 1 : 0;
    u32 i = ok ? sel[u*1024 + j] : 0u;
    int pos = (int)(i/3u);
    sa[tid] = (int)i - pos*3; sx[tid] = pos % W; sy[tid] = pos / W; sv[tid] = ok;
  }
  double acc[8];
  #pragma unroll
  for (int e=0;e<8;e++) acc[e]=0.0;
  __syncthreads();
  for (int ci0=0; ci0<256; ci0+=64){
    for (int el=tid; el<4608; el+=256){
      int e = el/576, r = el - e*576;
      int ci = r/9, q = r - ci*9, ky = q/3, kx = q - ky*3;
      int yy = sy[e]+ky-1, xx = sx[e]+kx-1;
      float v = 0.0f;
      if (yy>=0 && yy<H && xx>=0 && xx<W) v = fb[(size_t)(ci0+ci)*HW + (size_t)yy*W + xx];
      spd[el] = (double)v;
    }
    __syncthreads();
    const float* wq = wT + (size_t)(ci0*9)*256 + tid;
    for (int kk=0; kk<576; kk+=8){
      const float* wp = wq + (size_t)kk*256;
      float f0=wp[0],    f1=wp[256],  f2_=wp[512],  f3_=wp[768],
            f4_=wp[1024],f5_=wp[1280],f6_=wp[1536], f7_=wp[1792];
      double w0=(double)f0,  w1=(double)f1,  w2=(double)f2_, w3=(double)f3_,
             w4=(double)f4_, w5=(double)f5_, w6=(double)f6_, w7=(double)f7_;
      #pragma unroll
      for (int e=0;e<8;e++){
        const double* pe = spd + e*576 + kk;
        acc[e] += w0*pe[0]; acc[e] += w1*pe[1]; acc[e] += w2*pe[2]; acc[e] += w3*pe[3];
        acc[e] += w4*pe[4]; acc[e] += w5*pe[5]; acc[e] += w6*pe[6]; acc[e] += w7*pe[7];
      }
    }
    __syncthreads();
  }
  // alias tl2 onto spd (spd dead after loop; barrier above guarantees all reads done)
  double* tl2 = spd;   // [8][257] pitch 257
  {
    double bc = (double)cb[tid];
    #pragma unroll
    for (int e=0;e<8;e++){ double t = acc[e] + bc; tl2[e*257 + tid] = t > 0.0 ? t : 0.0; }
  }
  __syncthreads();
  if (tid < 40){
    int e = tid/5, q = tid - e*5;
    if (sv[e]){
      int a = sa[e];
      const float* wv = (q==0) ? (ow + a*256) : (dwt + (size_t)(a*4 + q-1)*256);
      double bias = (q==0) ? (double)ob[a] : (double)db[a*4 + q-1];
      double s = 0.0;
      for (int c=0;c<256;c++) s += (double)wv[c]*tl2[e*257 + c];
      s += bias;
      int j = j0 + e;
      if (q==0) rsc[(size_t)u*1024 + j] = s;
      else      rdl[((size_t)u*1024 + j)*4 + (q-1)] = s;
    }
  }
}

// ---------------- K3b: per-(level,image) bitonic sort of 1024 by exact fp64 score ----------------
__global__ __launch_bounds__(256) void k_sort1024(const double* __restrict__ rsc,
    const u32* __restrict__ cnt, u32* __restrict__ sord)
{
  const int u = blockIdx.x;
  const int cu = (int)cnt[u];
  const int tid = threadIdx.x;
  __shared__ u64 kk[1024];
  __shared__ u32 pp[1024];
  for (int i=tid;i<1024;i+=256){
    if (i < cu){ kk[i] = ordkey(rsc[(size_t)u*1024 + i]); pp[i] = (u32)i; }
    else       { kk[i] = 0ULL; pp[i] = 0xFFFFFFFFu; }
  }
  __syncthreads();
  for (int k=2;k<=1024;k<<=1){
    for (int j=k>>1;j>0;j>>=1){
      for (int i=tid;i<1024;i+=256){
        int l2 = i ^ j;
        if (l2 > i){
          u64 ka = kk[i], kb = kk[l2];
          u32 ia = pp[i], ib = pp[l2];
          bool before = (ka > kb) || (ka == kb && ia < ib);
          bool up = (i & k) == 0;
          if (up ? !before : before){
            kk[i]=kb; kk[l2]=ka; pp[i]=ib; pp[l2]=ia;
          }
        }
      }
      __syncthreads();
    }
  }
  for (int i=tid;i<1024;i+=256) sord[(size_t)u*1024 + i] = pp[i];
}

// ---------------- K4: decode boxes (exact mixed fp32/fp64 like reference) ----------------
__global__ __launch_bounds__(256) void k_decode(
    const double* __restrict__ rsc, const double* __restrict__ rdl,
    const u32* __restrict__ sel, const u32* __restrict__ sord,
    double* __restrict__ cbox, double* __restrict__ csc,
    u64* __restrict__ skey, u32* __restrict__ cnt)
{
#pragma clang fp contract(off)
  const int u = blockIdx.y, l = u >> 1, img = u & 1;
  const int slot = blockIdx.x*256 + threadIdx.x;
  if (slot >= c_K2[l]) return;
  const u32 entry = sord[(size_t)u*1024 + slot];
  const u32 idx = sel[u*1024 + entry];
  const double s = rsc[(size_t)u*1024 + entry];
  const double d0 = rdl[((size_t)u*1024+entry)*4+0], d1 = rdl[((size_t)u*1024+entry)*4+1];
  double d2 = rdl[((size_t)u*1024+entry)*4+2], d3 = rdl[((size_t)u*1024+entry)*4+3];
  const int pos = (int)(idx/3u), a = (int)idx - pos*3;
  const int W = c_W[l];
  const int x = pos % W, y = pos / W;
  const double rr = (a==0) ? 0.5 : ((a==1) ? 1.0 : 2.0);
  const double sz = (double)c_SZ[l];
  const double wa = sqrt(sz*sz/rr);
  const double ha = wa*rr;
  const float xs = (float)(x*c_STR[l]);
  const float ys = (float)(y*c_STR[l]);
  const float ax0 = xs + (float)(-0.5*wa);
  const float ax1 = xs + (float)( 0.5*wa);
  const float ay0 = ys + (float)(-0.5*ha);
  const float ay1 = ys + (float)( 0.5*ha);
  const float wf = ax1 - ax0;
  const float hf = ay1 - ay0;
  const float cxf = ax0 + 0.5f*wf;
  const float cyf = ay0 + 0.5f*hf;
  const double Wd = (double)wf, Hd = (double)hf, CX = (double)cxf, CY = (double)cyf;
  const double SCLAMP = 4.135166556742356;   // log(1000/16)
  if (d2 > SCLAMP) d2 = SCLAMP;
  if (d3 > SCLAMP) d3 = SCLAMP;
  double pcx = d0*Wd; pcx = pcx + CX;
  double pcy = d1*Hd; pcy = pcy + CY;
  const double pw = exp(d2)*Wd;
  const double ph = exp(d3)*Hd;
  double x0 = pcx - 0.5*pw;
  double y0 = pcy - 0.5*ph;
  double x1 = pcx + 0.5*pw;
  double y1 = pcy + 0.5*ph;
  x0 = fmin(fmax(x0, 0.0), 1216.0);
  x1 = fmin(fmax(x1, 0.0), 1216.0);
  y0 = fmin(fmax(y0, 0.0), 800.0);
  y1 = fmin(fmax(y1, 0.0), 800.0);
  const bool valid = (x1 - x0 > 0.0) && (y1 - y0 > 0.0);
  const double sm = valid ? s : -1e9;
  const int cp = c_LOFF[l] + slot;
  double* cb = cbox + ((size_t)img*M_CAND + cp)*4;
  cb[0]=x0; cb[1]=y0; cb[2]=x1; cb[3]=y1;
  csc[(size_t)img*M_CAND + cp] = sm;
  // packed key: truncated fp64 ordkey (13 low mantissa bits dropped; resolution
  // ~2e-12 rel << 1e-4 score gaps) | (8191-cp) => sort desc == (score desc, cp asc)
  skey[(size_t)img*8192 + cp] = (ordkey(sm) & ~(u64)0x1FFF) | (u64)(8191 - cp);
  if (valid) atomicAdd(&cnt[32+img], 1u);
}

// ---------------- K5: per-image bitonic sort of packed keys, fully in LDS ----------------
__global__ __launch_bounds__(1024) void k_sort(u64* __restrict__ key)
{
  const int img = blockIdx.x;
  u64* g = key + (size_t)img*8192;
  __shared__ u64 kk[8192];   // 64KB
  const int tid = threadIdx.x;
  for (int i=tid;i<8192;i+=1024) kk[i]=g[i];
  __syncthreads();
  for (int k=2;k<=8192;k<<=1){
    for (int j=k>>1;j>0;j>>=1){
      for (int i=tid;i<8192;i+=1024){
        int l = i ^ j;
        if (l > i){
          u64 ka = kk[i], kb = kk[l];
          bool before = (ka > kb);
          bool up = (i & k) == 0;
          if (up ? !before : before){ kk[i]=kb; kk[l]=ka; }
        }
      }
      __syncthreads();
    }
  }
  for (int i=tid;i<8192;i+=1024) g[i]=kk[i];
}

// ---------------- K5b: gather sorted boxes/scores ----------------
__global__ __launch_bounds__(256) void k_gather(const u64* __restrict__ skey,
    const double* __restrict__ cbox, const double* __restrict__ csc,
    double* __restrict__ sbox, double* __restrict__ ssc)
{
  int t = blockIdx.x*256 + threadIdx.x;
  if (t >= 2*M_CAND) return;
  int img = t / M_CAND, j = t - img*M_CAND;
  u32 b = 8191u - (u32)(skey[(size_t)img*8192 + j] & 0x1FFFull);
  const double* cb = cbox + ((size_t)img*M_CAND + b)*4;
  double* sb = sbox + ((size_t)img*M_CAND + j)*4;
  sb[0]=cb[0]; sb[1]=cb[1]; sb[2]=cb[2]; sb[3]=cb[3];
  ssc[(size_t)img*M_CAND + j] = csc[(size_t)img*M_CAND + b];
}

// ---------------- K6: pairwise IoU suppression bitmask ----------------
__global__ __launch_bounds__(256) void k_iou(const double* __restrict__ sbox, u64* __restrict__ mask)
{
#pragma clang fp contract(off)
  const int jb = blockIdx.x, ib = blockIdx.y, img = blockIdx.z;
  if (jb < ib) return;
  __shared__ double ibx[64][4];
  const int tid = threadIdx.x;
  const int lane = tid & 63, wv = tid >> 6;
  if (tid < 64){
    int ig = ib*64 + tid;
    if (ig < M_CAND){
      const double* b = sbox + ((size_t)img*M_CAND + ig)*4;
      ibx[tid][0]=b[0]; ibx[tid][1]=b[1]; ibx[tid][2]=b[2]; ibx[tid][3]=b[3];
    } else { ibx[tid][0]=0; ibx[tid][1]=0; ibx[tid][2]=0; ibx[tid][3]=0; }
  }
  const int jg = jb*64 + lane;
  double jx0=0,jy0=0,jx1=0,jy1=0;
  if (jg < M_CAND){
    const double* b = sbox + ((size_t)img*M_CAND + jg)*4;
    jx0=b[0]; jy0=b[1]; jx1=b[2]; jy1=b[3];
  }
  const double ja = (jx1-jx0)*(jy1-jy0);
  __syncthreads();
  for (int s=0;s<16;s++){
    const int il = wv*16 + s;
    const int ig = ib*64 + il;
    double bx0=ibx[il][0], by0=ibx[il][1], bx1=ibx[il][2], by1=ibx[il][3];
    double lt0 = bx0 > jx0 ? bx0 : jx0;
    double lt1 = by0 > jy0 ? by0 : jy0;
    double rb0 = bx1 < jx1 ? bx1 : jx1;
    double rb1 = by1 < jy1 ? by1 : jy1;
    double w = rb0-lt0; if (w<0.0) w=0.0;
    double h = rb1-lt1; if (h<0.0) h=0.0;
    double inter = w*h;
    double ia = (bx1-bx0)*(by1-by0);
    double un = ia + ja - inter; if (un < 1e-9) un = 1e-9;
    bool bit = (jg > ig) && (jg < M_CAND) && (inter/un > 0.7);
    u64 m = __ballot(bit);
    if (lane == 0) mask[((size_t)img*4800 + ig)*75 + jb] = m;
  }
}

// ---------------- K7: chunked greedy scan + output ----------------
__global__ __launch_bounds__(256) void k_nms(const u64* __restrict__ mask,
    const double* __restrict__ sbox, const double* __restrict__ ssc,
    const u32* __restrict__ cnt, float* __restrict__ out)
{
  const int img = blockIdx.x;
  const int tid = threadIdx.x;
  __shared__ u64 remv[75];
  __shared__ u64 diag[64];
  __shared__ int keep[1000];
  __shared__ int ck[64];
  __shared__ int s_kc, s_nk, s_done;
  if (tid < 75) remv[tid] = 0ULL;
  if (tid == 0){ s_kc = 0; s_done = 0; }
  int vc = (int)cnt[32+img]; if (vc > M_CAND) vc = M_CAND;
  const u64* mrow = mask + (size_t)img*4800*75;
  __syncthreads();
  for (int c=0; c<75; c++){
    if (c*64 >= vc) break;
    if (tid < 64) diag[tid] = mrow[(size_t)(c*64+tid)*75 + c];
    __syncthreads();
    if (tid == 0){
      u64 w = remv[c];
      int kc = s_kc, nk = 0;
      int lim = vc - c*64; if (lim > 64) lim = 64;
      for (int k=0;k<lim;k++){
        if (!((w >> k) & 1ULL)){
          int idx = c*64 + k;
          keep[kc] = idx;
          ck[nk++] = idx;
          kc++;
          if (kc >= 1000) break;
          w |= diag[k];
        }
      }
      s_kc = kc; s_nk = nk;
      if (kc >= 1000) s_done = 1;
    }
    __syncthreads();
    if (s_done) break;
    const int nk = s_nk;
    if (nk > 0){
      for (int c2 = c+1+tid; c2 < 75; c2 += 256){
        u64 a = remv[c2];
        for (int q=0;q<nk;q++) a |= mrow[(size_t)ck[q]*75 + c2];
        remv[c2] = a;
      }
    }
    __syncthreads();
  }
  __syncthreads();
  int kc = s_kc; if (kc > 1000) kc = 1000;
  for (int r = tid; r < 1000; r += 256){
    float v0=0.f,v1=0.f,v2=0.f,v3=0.f,v4=-1e9f;
    if (r < kc){
      int idx = keep[r];
      const double* b = sbox + ((size_t)img*M_CAND + idx)*4;
      v0=(float)b[0]; v1=(float)b[1]; v2=(float)b[2]; v3=(float)b[3];
      v4=(float)ssc[(size_t)img*M_CAND + idx];
    }
    float* o = out + ((size_t)img*1000 + r)*5;
    o[0]=v0; o[1]=v1; o[2]=v2; o[3]=v3; o[4]=v4;
  }
}

// ---------------- host ----------------
extern "C" void kernel_launch(void* const* d_in, const int* in_sizes, int n_in,
                              void* d_out, int out_size, void* d_ws, size_t ws_size,
                              hipStream_t stream)
{
  const float* feat[5];
  for (int i=0;i<5;i++) feat[i] = (const float*)d_in[i];
  const float* cw  = (const float*)d_in[5];
  const float* cb  = (const float*)d_in[6];
  const float* ow  = (const float*)d_in[7];
  const float* ob  = (const float*)d_in[8];
  const float* dwt = (const float*)d_in[9];
  const float* db  = (const float*)d_in[10];
  float* out = (float*)d_out;
  char* ws = (char*)d_ws;
  if (ws_size < WS_NEED) return;

  float*  ascore = (float*)(ws + OFF_ASC);
  u32*    thr    = (u32*)(ws + OFF_THR);
  u32*    quota  = (u32*)(ws + OFF_QUOTA);
  u32*    cnt    = (u32*)(ws + OFF_CNT);
  u32*    sel    = (u32*)(ws + OFF_SEL);
  double* rsc    = (double*)(ws + OFF_RSC);
  double* rdl    = (double*)(ws + OFF_RDL);
  u32*    sord   = (u32*)(ws + OFF_SORD);
  double* cbox   = (double*)(ws + OFF_CBOX);
  double* csc    = (double*)(ws + OFF_CSC);
  u64*    skey   = (u64*)(ws + OFF_SKEY);
  double* sbox   = (double*)(ws + OFF_SBOX);
  double* ssc    = (double*)(ws + OFF_SSC);
  u64*    mask   = (u64*)(ws + OFF_MASK);
  short*  wb2    = (short*)(ws + OFF_WB);
  float*  wT     = (float*)(ws + OFF_WT);

  k_prep<<<2304,256,0,stream>>>(cw, wb2, wT, cnt, skey);
  for (int l=0;l<5;l++){
    dim3 g((h_W[l]+63)/64, h_H[l], 2);
    k_convb<<<g,512,0,stream>>>(feat[l], wb2, cb, ow, ob,
                                ascore + h_SCOFF[l], h_H[l], h_W[l]);
  }
  k_radix32<<<10,1024,0,stream>>>(ascore, thr, quota);
  k_compact32<<<dim3(713,10),256,0,stream>>>(ascore, thr, quota, cnt, sel);
  k_recompute<<<dim3(128,10),256,0,stream>>>(feat[0],feat[1],feat[2],feat[3],feat[4],
                                             wT, cb, ow, ob, dwt, db, sel, cnt, rsc, rdl);
  k_sort1024<<<10,256,0,stream>>>(rsc, cnt, sord);
  k_decode<<<dim3(4,10),256,0,stream>>>(rsc, rdl, sel, sord, cbox, csc, skey, cnt);
  k_sort<<<2,1024,0,stream>>>(skey);
  k_gather<<<38,256,0,stream>>>(skey, cbox, csc, sbox, ssc);
  k_iou<<<dim3(75,75,2),256,0,stream>>>(sbox, mask);
  k_nms<<<2,256,0,stream>>>(mask, sbox, ssc, cnt, out);
}

// Round 6
// 1824.641 us; speedup vs baseline: 4.2248x; 1.2948x over previous
//
#include <hip/hip_runtime.h>
#include <math.h>

typedef unsigned int u32;
typedef unsigned long long u64;
typedef __attribute__((ext_vector_type(8))) short bf16x8;
typedef __attribute__((ext_vector_type(4))) float f32x4;
typedef __attribute__((ext_vector_type(4))) double f64x4;

// ---------------- level tables ----------------
__constant__ int c_W[5]   = {304,152,76,38,19};
__constant__ int c_H[5]   = {200,100,50,25,13};
__constant__ int c_STR[5] = {4,8,16,32,64};
__constant__ int c_SZ[5]  = {32,64,128,256,512};
__constant__ int c_S[5]   = {182400,45600,11400,2850,741};   // H*W*A
__constant__ int c_K1[5]  = {1024,1024,1024,1024,741};       // selection size (margin 24)
__constant__ int c_K2[5]  = {1000,1000,1000,1000,741};       // per-level keep
__constant__ u64 c_SCOFF[5] = {0,364800,456000,478800,484500}; // per-level base (x2 images)
__constant__ int c_LOFF[5] = {0,1000,2000,3000,4000};
// fused conv dispatch: block-prefix per level, x-blocks per level
__constant__ int c_PRE[6] = {0,2000,2600,2800,2850,2876};
__constant__ int c_NX[5]  = {5,3,2,1,1};

static const size_t h_SCOFF[5] = {0,364800,456000,478800,484500};

// ---------------- workspace layout ----------------
static constexpr size_t alignup(size_t x){ return (x + 255) & ~(size_t)255; }
static constexpr size_t N_SC   = 485982;     // total scores (both images)
static constexpr int    M_CAND = 4741;       // candidates per image
static constexpr size_t OFF_ASC   = 0;                                    // f32[N_SC]
static constexpr size_t OFF_THR   = alignup(OFF_ASC + N_SC*4);            // u32[16]
static constexpr size_t OFF_QUOTA = OFF_THR + 64;                         // u32[16]
static constexpr size_t OFF_CNT   = OFF_QUOTA + 64;                       // u32[64]
static constexpr size_t OFF_SEL   = alignup(OFF_CNT + 256);               // u32[10][1024]
static constexpr size_t OFF_RSC   = alignup(OFF_SEL + 10*1024*4);         // f64[10][1024]
static constexpr size_t OFF_RDL   = alignup(OFF_RSC + 10*1024*8);         // f64[10][1024][4]
static constexpr size_t OFF_SORD  = alignup(OFF_RDL + 10*1024*4*8);       // u32[10][1024]
static constexpr size_t OFF_CBOX  = alignup(OFF_SORD + 10*1024*4);        // f64[2][4741][4]
static constexpr size_t OFF_CSC   = alignup(OFF_CBOX + 2ull*M_CAND*4*8);  // f64[2][4741]
static constexpr size_t OFF_SKEY  = alignup(OFF_CSC + 2ull*M_CAND*8);     // u64[2][8192] packed (score|8191-cp)
static constexpr size_t OFF_SBOX  = alignup(OFF_SKEY + 2ull*8192*8);      // f64[2][4741][4]
static constexpr size_t OFF_SSC   = alignup(OFF_SBOX + 2ull*M_CAND*4*8);  // f64[2][4741]
static constexpr size_t OFF_MASK  = alignup(OFF_SSC + 2ull*M_CAND*8);     // u64[2][4800][75]
static constexpr size_t OFF_WB    = alignup(OFF_MASK + 2ull*4800*75*8);   // bf16[9][8][256][32]
static constexpr size_t OFF_WT    = alignup(OFF_WB + 589824ull*2);        // f32[2304][256] transposed conv w
static constexpr size_t WS_NEED   = OFF_WT + 589824ull*4;                 // ~12.7 MB

__device__ __forceinline__ u64 ordkey(double s){
  u64 b = (u64)__double_as_longlong(s);
  return b ^ ((b >> 63) ? 0xFFFFFFFFFFFFFFFFULL : 0x8000000000000000ULL);
}
__device__ __forceinline__ u32 ordkey32(float s){
  u32 b = __float_as_uint(s);
  return b ^ ((b >> 31) ? 0xFFFFFFFFu : 0x80000000u);
}
__device__ __forceinline__ short bf16rne(float f){
  u32 u = __float_as_uint(f);
  u32 r = (u + 0x7FFFu + ((u >> 16) & 1u)) >> 16;
  return (short)r;
}

// ---------------- K0: prep — counters, sort padding, bf16 weight pack, fp32 weight transpose ----
__global__ __launch_bounds__(256) void k_prep(const float* __restrict__ cw,
                                              short* __restrict__ wb2, float* __restrict__ wT,
                                              u32* cnt, u64* skey){
  int t = blockIdx.x*256 + threadIdx.x;   // grid = 2304*256 = 589824 exactly
  if (t < 64) cnt[t] = 0;
  const int npad = 8192 - M_CAND;
  if (t < 2*npad){
    int img = t / npad;
    int j = M_CAND + (t - img*npad);
    skey[(size_t)img*8192 + j] = 0ULL;   // sorts after every real entry
  }
  // bf16 MFMA pack: [tap][chunk][n][ci32]
  {
    int ci = t & 31, n = (t >> 5) & 255, chunk = (t >> 13) & 7, tap = t >> 16;
    int cig = chunk*32 + ci;
    int ky = tap/3, kx = tap - ky*3;
    wb2[t] = bf16rne(cw[((size_t)(n*256 + cig)*3 + ky)*3 + kx]);
  }
  // fp32 transpose for recompute: wT[k*256+co] = cw[co*2304+k]
  {
    int k = t >> 8, co = t & 255;
    wT[t] = cw[(size_t)co*2304 + k];
  }
}

// ---------------- K1: bf16 MFMA implicit-GEMM conv3x3 + ReLU + obj 1x1 (approx) ----
// ALL levels in one launch; block: 512 thr = 8 waves; 64-pixel strip at row y.
__global__ __launch_bounds__(512) void k_convb(
    const float* __restrict__ f2, const float* __restrict__ f3,
    const float* __restrict__ f4, const float* __restrict__ f5,
    const float* __restrict__ f6, const short* __restrict__ wb2,
    const float* __restrict__ cb, const float* __restrict__ ow,
    const float* __restrict__ ob, float* __restrict__ ascore)
{
  __shared__ __align__(16) short Ap[198*136];   // [ry*66+cx][ci(128, pitch136)] bf16 ~52.6KB
  __shared__ __align__(16) short Bt[256*40];    // [n][ci32 pitch40] bf16 = 20KB
  __shared__ float ps[192];                     // [3][64] partial scores
  const int tid = threadIdx.x;
  int bid = blockIdx.x;
  int l = 0;
  while (bid >= c_PRE[l+1]) ++l;
  bid -= c_PRE[l];
  const int W = c_W[l], H = c_H[l], nx = c_NX[l];
  const int xb = bid % nx; int rem = bid / nx;
  const int y = rem % H; const int img = rem / H;
  const int x0 = xb*64;
  const size_t HW = (size_t)H*W;
  const float* fl = (l==0)?f2:(l==1)?f3:(l==2)?f4:(l==3)?f5:f6;
  const float* fb = fl + (size_t)img*256*HW;
  for (int e=tid;e<192;e+=512) ps[e]=0.f;

  const int wid = tid>>6, lane = tid&63;
  const int wr = wid>>2, wc = wid&3;
  const int l15 = lane&15, lg = lane>>4;

  f32x4 acc[2][4];
  #pragma unroll
  for(int a=0;a<2;a++)
    #pragma unroll
    for(int b=0;b<4;b++) acc[a][b] = (f32x4){0.f,0.f,0.f,0.f};

  for (int half=0; half<2; half++){
    __syncthreads();
    // stage A: 128 ci x (3 ry x 66 cx); coalesced over cx, bank-safe pitch 136
    for (int e=tid; e<25344; e+=512){
      int ci = e/198, r = e - ci*198;          // r = ry*66+cx
      int ry = r/66, cx = r - ry*66;
      int yy = y + ry - 1, xx = x0 + cx - 1;
      float v = 0.f;
      if (yy>=0 && yy<H && xx>=0 && xx<W)
        v = fb[(size_t)(half*128+ci)*HW + (size_t)yy*W + xx];
      Ap[r*136 + ci] = bf16rne(v);
    }
    for (int tap=0; tap<9; tap++){
      const int kyy = tap/3, kxx = tap - kyy*3;
      for (int c2=0; c2<4; c2++){
        __syncthreads();
        { // stage B tile (16KB contiguous source), pitch-40 LDS
          const short* bs = wb2 + (((tap<<3) + (half<<2) + c2) << 13);
          for (int p=tid; p<1024; p+=512){
            int n = p>>2, seg = p&3;
            *(uint4*)(Bt + n*40 + (seg<<3)) = *(const uint4*)(bs + (n<<5) + (seg<<3));
          }
        }
        __syncthreads();
        const int colb = kyy*66 + wr*32 + l15 + kxx;
        const int cio  = c2*32 + lg*8;
        bf16x8 a0 = *(const bf16x8*)(Ap + colb*136 + cio);
        bf16x8 a1 = *(const bf16x8*)(Ap + (colb+16)*136 + cio);
        #pragma unroll
        for (int nf=0; nf<4; nf++){
          bf16x8 b = *(const bf16x8*)(Bt + (wc*64 + nf*16 + l15)*40 + lg*8);
          acc[0][nf] = __builtin_amdgcn_mfma_f32_16x16x32_bf16(a0, b, acc[0][nf], 0,0,0);
          acc[1][nf] = __builtin_amdgcn_mfma_f32_16x16x32_bf16(a1, b, acc[1][nf], 0,0,0);
        }
      }
    }
  }
  // epilogue: bias + relu + obj 1x1 (fp32), reduce over n
  float p[3][2][4];
  #pragma unroll
  for (int a=0;a<3;a++)
    #pragma unroll
    for(int mf=0;mf<2;mf++)
      #pragma unroll
      for(int r=0;r<4;r++) p[a][mf][r]=0.f;
  #pragma unroll
  for (int nf=0; nf<4; nf++){
    int n = wc*64 + nf*16 + l15;
    float cbn = cb[n];
    float w0 = ow[n], w1 = ow[256+n], w2 = ow[512+n];
    #pragma unroll
    for (int mf=0; mf<2; mf++)
      #pragma unroll
      for (int r=0;r<4;r++){
        float t = acc[mf][nf][r] + cbn;
        t = t>0.f ? t : 0.f;
        p[0][mf][r] += w0*t; p[1][mf][r] += w1*t; p[2][mf][r] += w2*t;
      }
  }
  #pragma unroll
  for (int a=0;a<3;a++)
    #pragma unroll
    for (int mf=0;mf<2;mf++)
      #pragma unroll
      for (int r=0;r<4;r++){
        float v = p[a][mf][r];
        v += __shfl_xor(v, 1); v += __shfl_xor(v, 2);
        v += __shfl_xor(v, 4); v += __shfl_xor(v, 8);
        p[a][mf][r] = v;
      }
  if (l15 == 0){
    #pragma unroll
    for (int a=0;a<3;a++)
      #pragma unroll
      for (int mf=0;mf<2;mf++)
        #pragma unroll
        for (int r=0;r<4;r++)
          atomicAdd(&ps[a*64 + wr*32 + mf*16 + lg*4 + r], p[a][mf][r]);
  }
  __syncthreads();
  float* so = ascore + c_SCOFF[l] + (size_t)img*HW*3;
  for (int e=tid; e<192; e+=512){
    int a = e>>6, px = e&63;
    int xg = x0 + px;
    if (xg < W) so[((size_t)y*W + xg)*3 + a] = ps[e] + ob[a];
  }
}

// ---------------- K2: per-(level,image) radix-select of K1-th largest fp32 key ----------------
// (round-4 verified scalar version)
__global__ __launch_bounds__(1024) void k_radix32(const float* __restrict__ ascore,
                                                  u32* __restrict__ thr, u32* __restrict__ quota)
{
  const int u = blockIdx.x, l = u >> 1, img = u & 1;
  const int n = c_S[l], k = c_K1[l];
  const int tid = threadIdx.x;
  if (n <= k){ if (tid==0){ thr[u]=0u; quota[u]=0xFFFFFFFFu; } return; }
  const float* sc = ascore + c_SCOFF[l] + (size_t)img*n;
  __shared__ u32 hist[2048];
  __shared__ u32 grp[32];
  __shared__ u32 s_pref;
  __shared__ u32 s_rem;
  if (tid==0){ s_pref=0u; s_rem=(u32)k; }
  const int shifts[3] = {21,10,0};
  const int bitsA[3]  = {11,11,10};
  for (int p=0;p<3;p++){
    const int nb = 1 << bitsA[p];
    for (int i=tid;i<nb;i+=1024) hist[i]=0u;
    __syncthreads();
    const u32 pref = s_pref;
    const int sh = shifts[p], hb = bitsA[p];
    for (int i=tid;i<n;i+=1024){
      u32 key = ordkey32(sc[i]);
      bool m = (p==0) || ((key >> (sh+hb)) == pref);
      if (m) atomicAdd(&hist[(key>>sh) & (u32)(nb-1)], 1u);
    }
    __syncthreads();
    const int per = nb >> 5;
    if (tid < 32){ u32 s=0; for (int q=0;q<per;q++) s += hist[tid*per+q]; grp[tid]=s; }
    __syncthreads();
    if (tid==0){
      u32 rem = s_rem, cum = 0;
      int g = 31;
      for (; g>0; g--){ if (cum + grp[g] >= rem) break; cum += grp[g]; }
      int b = (g+1)*per - 1;
      for (; b > g*per; b--){ if (cum + hist[b] >= rem) break; cum += hist[b]; }
      s_pref = (s_pref << hb) | (u32)b;
      s_rem = rem - cum;
    }
    __syncthreads();
  }
  if (tid==0){ thr[u] = s_pref; quota[u] = s_rem; }
}

// ---------------- K2b: compact selected indices ----------------
__global__ __launch_bounds__(256) void k_compact32(const float* __restrict__ ascore,
    const u32* __restrict__ thr, const u32* __restrict__ quota,
    u32* __restrict__ cnt, u32* __restrict__ sel)
{
  const int u = blockIdx.y, l = u >> 1, img = u & 1;
  const int n = c_S[l];
  const int i = blockIdx.x*256 + threadIdx.x;
  if (i >= n) return;
  const float* sc = ascore + c_SCOFF[l] + (size_t)img*n;
  u32 key = ordkey32(sc[i]);
  u32 q = quota[u];
  bool take = false;
  if (q == 0xFFFFFFFFu) take = true;           // n <= k: take all
  else {
    u32 t = thr[u];
    if (key > t) take = true;
    else if (key == t){ if (atomicAdd(&cnt[16+u],1u) < q) take = true; }
  }
  if (take){ u32 p = atomicAdd(&cnt[u],1u); if (p < 1024u) sel[u*1024 + p] = (u32)i; }
}

// ---------------- K3: fp64-MFMA recompute with RUNTIME-PROBED fragment layout ----------------
// block = 16 entries (M); 256 thr = 4 waves; each wave owns 64 co (4 n-tiles of 16).
// Layout discovery: 3 probe MFMAs tell us A/B lane mappings and exact D (row,col) per reg.
__global__ __launch_bounds__(256) void k_recompute(
    const float* __restrict__ f2, const float* __restrict__ f3,
    const float* __restrict__ f4, const float* __restrict__ f5,
    const float* __restrict__ f6,
    const float* __restrict__ wT, const float* __restrict__ cb,
    const float* __restrict__ ow, const float* __restrict__ ob,
    const float* __restrict__ dwt, const float* __restrict__ db,
    const u32* __restrict__ sel, const u32* __restrict__ cnt,
    double* __restrict__ rsc, double* __restrict__ rdl)
{
  const int u = blockIdx.y, l = u >> 1, img = u & 1;
  const int j0 = blockIdx.x * 16;
  const int cu = (int)cnt[u];
  if (j0 >= cu) return;
  const int W = c_W[l], H = c_H[l];
  const size_t HW = (size_t)W*H;
  const float* fl = (l==0)?f2:(l==1)?f3:(l==2)?f4:(l==3)?f5:f6;
  const float* fb = fl + (size_t)img*256*HW;
  __shared__ __align__(16) float spA[576*17];   // 39.2KB, [k within chunk][entry] pitch 17
  __shared__ int sx[16], sy[16], sa[16];
  const int tid = threadIdx.x;
  if (tid < 16){
    int j = j0 + tid; int ok = (j < cu) ? 1 : 0;
    u32 i = ok ? sel[u*1024 + j] : 0u;
    int pos = (int)(i/3u);
    sa[tid] = (int)i - pos*3; sx[tid] = pos % W; sy[tid] = pos / W;
  }
  const int wid = tid >> 6, lane = tid & 63;

  // ---- layout probes (3 MFMAs) ----
  // Probe 1: a=lane, b=1 (B-layout-independent). D[i][j] = sum_k laneA(i,k).
  //   (lane0,reg0) holds D[0][0] under any sane mapping: A1(lane=i+16k) -> 96; A2(lane=4i+k) -> 6.
  const f64x4 pz = (f64x4){0.0,0.0,0.0,0.0};
  f64x4 p1 = __builtin_amdgcn_mfma_f64_16x16x4f64((double)lane, 1.0, pz, 0,0,0);
  const double v0 = __shfl(p1[0], 0);
  const bool isA1 = (v0 > 50.0);
  // Probe 2: a = delta_{k=0} (under discovered A), b = lane. D[i][j] = laneB(0,j).
  //   B1(lane=j+16k) -> j; B2(lane=4j+k) -> 4j. Ballot on ==1.0 disambiguates.
  const double aD = isA1 ? ((lane<16)?1.0:0.0) : (((lane&3)==0)?1.0:0.0);
  f64x4 p2 = __builtin_amdgcn_mfma_f64_16x16x4f64(aD, (double)lane, pz, 0,0,0);
  const bool own1 = (p2[0]==1.0)||(p2[1]==1.0)||(p2[2]==1.0)||(p2[3]==1.0);
  const bool isB1 = (__ballot(own1) != 0ull);
  // Probe 3: a = row-index pattern, b = delta_{k=0}. D[i][j] = i -> row per (lane,reg).
  const double aI = (double)(isA1 ? (lane&15) : (lane>>2));
  const double bD = isB1 ? ((lane<16)?1.0:0.0) : (((lane&3)==0)?1.0:0.0);
  f64x4 p3 = __builtin_amdgcn_mfma_f64_16x16x4f64(aI, bD, pz, 0,0,0);
  int row_[4], col_[4];
  const double cs = isB1 ? 1.0 : 0.25;
  #pragma unroll
  for (int r=0;r<4;r++){ col_[r] = (int)(p2[r]*cs); row_[r] = (int)p3[r]; }
  const int mrow = isA1 ? (lane&15) : (lane>>2);
  const int kA   = isA1 ? (lane>>4) : (lane&3);
  const int jB   = isB1 ? (lane&15) : (lane>>2);
  const int kB   = isB1 ? (lane>>4) : (lane&3);

  f64x4 acc[4];
  #pragma unroll
  for (int nt=0;nt<4;nt++) acc[nt] = pz;
  __syncthreads();
  for (int ci0=0; ci0<256; ci0+=64){
    for (int el=tid; el<9216; el+=256){
      int e = el/576, r = el - e*576;
      int ci = r/9, q = r - ci*9, ky = q/3, kx = q - ky*3;
      int yy = sy[e]+ky-1, xx = sx[e]+kx-1;
      float v = 0.0f;
      if (yy>=0 && yy<H && xx>=0 && xx<W) v = fb[(size_t)(ci0+ci)*HW + (size_t)yy*W + xx];
      spA[r*17 + e] = v;
    }
    __syncthreads();
    const float* wb = wT + (size_t)(ci0*9)*256 + (wid<<6) + jB;
    #pragma unroll 2
    for (int kt=0; kt<144; kt++){
      double a = (double)spA[(kt*4 + kA)*17 + mrow];
      const float* bp = wb + (size_t)(kt*4 + kB)*256;
      #pragma unroll
      for (int nt=0; nt<4; nt++){
        double b = (double)bp[nt*16];
        acc[nt] = __builtin_amdgcn_mfma_f64_16x16x4f64(a, b, acc[nt], 0,0,0);
      }
    }
    __syncthreads();
  }
  // epilogue: bias + relu into tl2[16][257] f64 (aliased onto spA; all reads drained)
  double* tl2 = (double*)spA;
  #pragma unroll
  for (int nt=0; nt<4; nt++){
    #pragma unroll
    for (int r=0;r<4;r++){
      const int co = (wid<<6) + nt*16 + col_[r];
      double t = acc[nt][r] + (double)cb[co];
      tl2[row_[r]*257 + co] = t > 0.0 ? t : 0.0;
    }
  }
  __syncthreads();
  if (tid < 80){
    int e = tid/5, q = tid - e*5;
    if (j0 + e < cu){
      int a = sa[e];
      const float* wv = (q==0) ? (ow + a*256) : (dwt + (size_t)(a*4 + q-1)*256);
      double bias = (q==0) ? (double)ob[a] : (double)db[a*4 + q-1];
      double s = 0.0;
      for (int c=0;c<256;c++) s += (double)wv[c]*tl2[e*257 + c];
      s += bias;
      int j = j0 + e;
      if (q==0) rsc[(size_t)u*1024 + j] = s;
      else      rdl[((size_t)u*1024 + j)*4 + (q-1)] = s;
    }
  }
}

// ---------------- K3b: per-(level,image) bitonic sort of 1024 by exact fp64 score ----------------
__global__ __launch_bounds__(256) void k_sort1024(const double* __restrict__ rsc,
    const u32* __restrict__ cnt, u32* __restrict__ sord)
{
  const int u = blockIdx.x;
  const int cu = (int)cnt[u];
  const int tid = threadIdx.x;
  __shared__ u64 kk[1024];
  __shared__ u32 pp[1024];
  for (int i=tid;i<1024;i+=256){
    if (i < cu){ kk[i] = ordkey(rsc[(size_t)u*1024 + i]); pp[i] = (u32)i; }
    else       { kk[i] = 0ULL; pp[i] = 0xFFFFFFFFu; }
  }
  __syncthreads();
  for (int k=2;k<=1024;k<<=1){
    for (int j=k>>1;j>0;j>>=1){
      for (int i=tid;i<1024;i+=256){
        int l2 = i ^ j;
        if (l2 > i){
          u64 ka = kk[i], kb = kk[l2];
          u32 ia = pp[i], ib = pp[l2];
          bool before = (ka > kb) || (ka == kb && ia < ib);
          bool up = (i & k) == 0;
          if (up ? !before : before){
            kk[i]=kb; kk[l2]=ka; pp[i]=ib; pp[l2]=ia;
          }
        }
      }
      __syncthreads();
    }
  }
  for (int i=tid;i<1024;i+=256) sord[(size_t)u*1024 + i] = pp[i];
}

// ---------------- K4: decode boxes (exact mixed fp32/fp64 like reference) ----------------
__global__ __launch_bounds__(256) void k_decode(
    const double* __restrict__ rsc, const double* __restrict__ rdl,
    const u32* __restrict__ sel, const u32* __restrict__ sord,
    double* __restrict__ cbox, double* __restrict__ csc,
    u64* __restrict__ skey, u32* __restrict__ cnt)
{
#pragma clang fp contract(off)
  const int u = blockIdx.y, l = u >> 1, img = u & 1;
  const int slot = blockIdx.x*256 + threadIdx.x;
  if (slot >= c_K2[l]) return;
  const u32 entry = sord[(size_t)u*1024 + slot];
  const u32 idx = sel[u*1024 + entry];
  const double s = rsc[(size_t)u*1024 + entry];
  const double d0 = rdl[((size_t)u*1024+entry)*4+0], d1 = rdl[((size_t)u*1024+entry)*4+1];
  double d2 = rdl[((size_t)u*1024+entry)*4+2], d3 = rdl[((size_t)u*1024+entry)*4+3];
  const int pos = (int)(idx/3u), a = (int)idx - pos*3;
  const int W = c_W[l];
  const int x = pos % W, y = pos / W;
  const double rr = (a==0) ? 0.5 : ((a==1) ? 1.0 : 2.0);
  const double sz = (double)c_SZ[l];
  const double wa = sqrt(sz*sz/rr);
  const double ha = wa*rr;
  const float xs = (float)(x*c_STR[l]);
  const float ys = (float)(y*c_STR[l]);
  const float ax0 = xs + (float)(-0.5*wa);
  const float ax1 = xs + (float)( 0.5*wa);
  const float ay0 = ys + (float)(-0.5*ha);
  const float ay1 = ys + (float)( 0.5*ha);
  const float wf = ax1 - ax0;
  const float hf = ay1 - ay0;
  const float cxf = ax0 + 0.5f*wf;
  const float cyf = ay0 + 0.5f*hf;
  const double Wd = (double)wf, Hd = (double)hf, CX = (double)cxf, CY = (double)cyf;
  const double SCLAMP = 4.135166556742356;   // log(1000/16)
  if (d2 > SCLAMP) d2 = SCLAMP;
  if (d3 > SCLAMP) d3 = SCLAMP;
  double pcx = d0*Wd; pcx = pcx + CX;
  double pcy = d1*Hd; pcy = pcy + CY;
  const double pw = exp(d2)*Wd;
  const double ph = exp(d3)*Hd;
  double x0 = pcx - 0.5*pw;
  double y0 = pcy - 0.5*ph;
  double x1 = pcx + 0.5*pw;
  double y1 = pcy + 0.5*ph;
  x0 = fmin(fmax(x0, 0.0), 1216.0);
  x1 = fmin(fmax(x1, 0.0), 1216.0);
  y0 = fmin(fmax(y0, 0.0), 800.0);
  y1 = fmin(fmax(y1, 0.0), 800.0);
  const bool valid = (x1 - x0 > 0.0) && (y1 - y0 > 0.0);
  const double sm = valid ? s : -1e9;
  const int cp = c_LOFF[l] + slot;
  double* cb = cbox + ((size_t)img*M_CAND + cp)*4;
  cb[0]=x0; cb[1]=y0; cb[2]=x1; cb[3]=y1;
  csc[(size_t)img*M_CAND + cp] = sm;
  // packed key: truncated fp64 ordkey (13 low mantissa bits dropped; resolution
  // ~2e-12 rel << 1e-4 score gaps) | (8191-cp) => sort desc == (score desc, cp asc)
  skey[(size_t)img*8192 + cp] = (ordkey(sm) & ~(u64)0x1FFF) | (u64)(8191 - cp);
  if (valid) atomicAdd(&cnt[32+img], 1u);
}

// ---------------- K5: per-image bitonic sort of packed keys, fully in LDS ----------------
__global__ __launch_bounds__(1024) void k_sort(u64* __restrict__ key)
{
  const int img = blockIdx.x;
  u64* g = key + (size_t)img*8192;
  __shared__ u64 kk[8192];   // 64KB
  const int tid = threadIdx.x;
  for (int i=tid;i<8192;i+=1024) kk[i]=g[i];
  __syncthreads();
  for (int k=2;k<=8192;k<<=1){
    for (int j=k>>1;j>0;j>>=1){
      for (int i=tid;i<8192;i+=1024){
        int l = i ^ j;
        if (l > i){
          u64 ka = kk[i], kb = kk[l];
          bool before = (ka > kb);
          bool up = (i & k) == 0;
          if (up ? !before : before){ kk[i]=kb; kk[l]=ka; }
        }
      }
      __syncthreads();
    }
  }
  for (int i=tid;i<8192;i+=1024) g[i]=kk[i];
}

// ---------------- K5b: gather sorted boxes/scores ----------------
__global__ __launch_bounds__(256) void k_gather(const u64* __restrict__ skey,
    const double* __restrict__ cbox, const double* __restrict__ csc,
    double* __restrict__ sbox, double* __restrict__ ssc)
{
  int t = blockIdx.x*256 + threadIdx.x;
  if (t >= 2*M_CAND) return;
  int img = t / M_CAND, j = t - img*M_CAND;
  u32 b = 8191u - (u32)(skey[(size_t)img*8192 + j] & 0x1FFFull);
  const double* cb = cbox + ((size_t)img*M_CAND + b)*4;
  double* sb = sbox + ((size_t)img*M_CAND + j)*4;
  sb[0]=cb[0]; sb[1]=cb[1]; sb[2]=cb[2]; sb[3]=cb[3];
  ssc[(size_t)img*M_CAND + j] = csc[(size_t)img*M_CAND + b];
}

// ---------------- K6: pairwise IoU suppression bitmask ----------------
__global__ __launch_bounds__(256) void k_iou(const double* __restrict__ sbox, u64* __restrict__ mask)
{
#pragma clang fp contract(off)
  const int jb = blockIdx.x, ib = blockIdx.y, img = blockIdx.z;
  if (jb < ib) return;
  __shared__ double ibx[64][4];
  const int tid = threadIdx.x;
  const int lane = tid & 63, wv = tid >> 6;
  if (tid < 64){
    int ig = ib*64 + tid;
    if (ig < M_CAND){
      const double* b = sbox + ((size_t)img*M_CAND + ig)*4;
      ibx[tid][0]=b[0]; ibx[tid][1]=b[1]; ibx[tid][2]=b[2]; ibx[tid][3]=b[3];
    } else { ibx[tid][0]=0; ibx[tid][1]=0; ibx[tid][2]=0; ibx[tid][3]=0; }
  }
  const int jg = jb*64 + lane;
  double jx0=0,jy0=0,jx1=0,jy1=0;
  if (jg < M_CAND){
    const double* b = sbox + ((size_t)img*M_CAND + jg)*4;
    jx0=b[0]; jy0=b[1]; jx1=b[2]; jy1=b[3];
  }
  const double ja = (jx1-jx0)*(jy1-jy0);
  __syncthreads();
  for (int s=0;s<16;s++){
    const int il = wv*16 + s;
    const int ig = ib*64 + il;
    double bx0=ibx[il][0], by0=ibx[il][1], bx1=ibx[il][2], by1=ibx[il][3];
    double lt0 = bx0 > jx0 ? bx0 : jx0;
    double lt1 = by0 > jy0 ? by0 : jy0;
    double rb0 = bx1 < jx1 ? bx1 : jx1;
    double rb1 = by1 < jy1 ? by1 : jy1;
    double w = rb0-lt0; if (w<0.0) w=0.0;
    double h = rb1-lt1; if (h<0.0) h=0.0;
    double inter = w*h;
    double ia = (bx1-bx0)*(by1-by0);
    double un = ia + ja - inter; if (un < 1e-9) un = 1e-9;
    bool bit = (jg > ig) && (jg < M_CAND) && (inter/un > 0.7);
    u64 m = __ballot(bit);
    if (lane == 0) mask[((size_t)img*4800 + ig)*75 + jb] = m;
  }
}

// ---------------- K7: chunked greedy scan + output ----------------
__global__ __launch_bounds__(256) void k_nms(const u64* __restrict__ mask,
    const double* __restrict__ sbox, const double* __restrict__ ssc,
    const u32* __restrict__ cnt, float* __restrict__ out)
{
  const int img = blockIdx.x;
  const int tid = threadIdx.x;
  __shared__ u64 remv[75];
  __shared__ u64 diag[64];
  __shared__ int keep[1000];
  __shared__ int ck[64];
  __shared__ int s_kc, s_nk, s_done;
  if (tid < 75) remv[tid] = 0ULL;
  if (tid == 0){ s_kc = 0; s_done = 0; }
  int vc = (int)cnt[32+img]; if (vc > M_CAND) vc = M_CAND;
  const u64* mrow = mask + (size_t)img*4800*75;
  __syncthreads();
  for (int c=0; c<75; c++){
    if (c*64 >= vc) break;
    if (tid < 64) diag[tid] = mrow[(size_t)(c*64+tid)*75 + c];
    __syncthreads();
    if (tid == 0){
      u64 w = remv[c];
      int kc = s_kc, nk = 0;
      int lim = vc - c*64; if (lim > 64) lim = 64;
      for (int k=0;k<lim;k++){
        if (!((w >> k) & 1ULL)){
          int idx = c*64 + k;
          keep[kc] = idx;
          ck[nk++] = idx;
          kc++;
          if (kc >= 1000) break;
          w |= diag[k];
        }
      }
      s_kc = kc; s_nk = nk;
      if (kc >= 1000) s_done = 1;
    }
    __syncthreads();
    if (s_done) break;
    const int nk = s_nk;
    if (nk > 0){
      for (int c2 = c+1+tid; c2 < 75; c2 += 256){
        u64 a = remv[c2];
        for (int q=0;q<nk;q++) a |= mrow[(size_t)ck[q]*75 + c2];
        remv[c2] = a;
      }
    }
    __syncthreads();
  }
  __syncthreads();
  int kc = s_kc; if (kc > 1000) kc = 1000;
  for (int r = tid; r < 1000; r += 256){
    float v0=0.f,v1=0.f,v2=0.f,v3=0.f,v4=-1e9f;
    if (r < kc){
      int idx = keep[r];
      const double* b = sbox + ((size_t)img*M_CAND + idx)*4;
      v0=(float)b[0]; v1=(float)b[1]; v2=(float)b[2]; v3=(float)b[3];
      v4=(float)ssc[(size_t)img*M_CAND + idx];
    }
    float* o = out + ((size_t)img*1000 + r)*5;
    o[0]=v0; o[1]=v1; o[2]=v2; o[3]=v3; o[4]=v4;
  }
}

// ---------------- host ----------------
extern "C" void kernel_launch(void* const* d_in, const int* in_sizes, int n_in,
                              void* d_out, int out_size, void* d_ws, size_t ws_size,
                              hipStream_t stream)
{
  const float* feat[5];
  for (int i=0;i<5;i++) feat[i] = (const float*)d_in[i];
  const float* cw  = (const float*)d_in[5];
  const float* cb  = (const float*)d_in[6];
  const float* ow  = (const float*)d_in[7];
  const float* ob  = (const float*)d_in[8];
  const float* dwt = (const float*)d_in[9];
  const float* db  = (const float*)d_in[10];
  float* out = (float*)d_out;
  char* ws = (char*)d_ws;
  if (ws_size < WS_NEED) return;

  float*  ascore = (float*)(ws + OFF_ASC);
  u32*    thr    = (u32*)(ws + OFF_THR);
  u32*    quota  = (u32*)(ws + OFF_QUOTA);
  u32*    cnt    = (u32*)(ws + OFF_CNT);
  u32*    sel    = (u32*)(ws + OFF_SEL);
  double* rsc    = (double*)(ws + OFF_RSC);
  double* rdl    = (double*)(ws + OFF_RDL);
  u32*    sord   = (u32*)(ws + OFF_SORD);
  double* cbox   = (double*)(ws + OFF_CBOX);
  double* csc    = (double*)(ws + OFF_CSC);
  u64*    skey   = (u64*)(ws + OFF_SKEY);
  double* sbox   = (double*)(ws + OFF_SBOX);
  double* ssc    = (double*)(ws + OFF_SSC);
  u64*    mask   = (u64*)(ws + OFF_MASK);
  short*  wb2    = (short*)(ws + OFF_WB);
  float*  wT     = (float*)(ws + OFF_WT);

  k_prep<<<2304,256,0,stream>>>(cw, wb2, wT, cnt, skey);
  k_convb<<<2876,512,0,stream>>>(feat[0],feat[1],feat[2],feat[3],feat[4],
                                 wb2, cb, ow, ob, ascore);
  k_radix32<<<10,1024,0,stream>>>(ascore, thr, quota);
  k_compact32<<<dim3(713,10),256,0,stream>>>(ascore, thr, quota, cnt, sel);
  k_recompute<<<dim3(64,10),256,0,stream>>>(feat[0],feat[1],feat[2],feat[3],feat[4],
                                            wT, cb, ow, ob, dwt, db, sel, cnt, rsc, rdl);
  k_sort1024<<<10,256,0,stream>>>(rsc, cnt, sord);
  k_decode<<<dim3(4,10),256,0,stream>>>(rsc, rdl, sel, sord, cbox, csc, skey, cnt);
  k_sort<<<2,1024,0,stream>>>(skey);
  k_gather<<<38,256,0,stream>>>(skey, cbox, csc, sbox, ssc);
  k_iou<<<dim3(75,75,2),256,0,stream>>>(sbox, mask);
  k_nms<<<2,256,0,stream>>>(mask, sbox, ssc, cnt, out);
}

// Round 7
// 1667.519 us; speedup vs baseline: 4.6229x; 1.0942x over previous
//
#include <hip/hip_runtime.h>
#include <math.h>

typedef unsigned int u32;
typedef unsigned long long u64;
typedef __attribute__((ext_vector_type(8))) short bf16x8;
typedef __attribute__((ext_vector_type(4))) float f32x4;
typedef __attribute__((ext_vector_type(4))) double f64x4;

// ---------------- level tables ----------------
__constant__ int c_W[5]   = {304,152,76,38,19};
__constant__ int c_H[5]   = {200,100,50,25,13};
__constant__ int c_STR[5] = {4,8,16,32,64};
__constant__ int c_SZ[5]  = {32,64,128,256,512};
__constant__ int c_S[5]   = {182400,45600,11400,2850,741};   // H*W*A
__constant__ int c_K1[5]  = {1024,1024,1024,1024,741};       // selection size (margin 24)
__constant__ int c_K2[5]  = {1000,1000,1000,1000,741};       // per-level keep
__constant__ u64 c_SCOFF[5] = {0,364800,456000,478800,484500}; // per-level base (x2 images)
__constant__ int c_LOFF[5] = {0,1000,2000,3000,4000};
// fused conv dispatch: block-prefix per level, x-blocks per level
__constant__ int c_PRE[6] = {0,2000,2600,2800,2850,2876};
__constant__ int c_NX[5]  = {5,3,2,1,1};

static const size_t h_SCOFF[5] = {0,364800,456000,478800,484500};

// ---------------- workspace layout ----------------
static constexpr size_t alignup(size_t x){ return (x + 255) & ~(size_t)255; }
static constexpr size_t N_SC   = 485982;     // total scores (both images)
static constexpr int    M_CAND = 4741;       // candidates per image
static constexpr size_t OFF_ASC   = 0;                                    // f32[N_SC]
static constexpr size_t OFF_THR   = alignup(OFF_ASC + N_SC*4);            // u32[16]
static constexpr size_t OFF_QUOTA = OFF_THR + 64;                         // u32[16]
static constexpr size_t OFF_CNT   = OFF_QUOTA + 64;                       // u32[64]
static constexpr size_t OFF_SEL   = alignup(OFF_CNT + 256);               // u32[10][1024]
static constexpr size_t OFF_RSC   = alignup(OFF_SEL + 10*1024*4);         // f64[10][1024]
static constexpr size_t OFF_RDL   = alignup(OFF_RSC + 10*1024*8);         // f64[10][1024][4]
static constexpr size_t OFF_SORD  = alignup(OFF_RDL + 10*1024*4*8);       // u32[10][1024]
static constexpr size_t OFF_CBOX  = alignup(OFF_SORD + 10*1024*4);        // f64[2][4741][4]
static constexpr size_t OFF_CSC   = alignup(OFF_CBOX + 2ull*M_CAND*4*8);  // f64[2][4741]
static constexpr size_t OFF_SKEY  = alignup(OFF_CSC + 2ull*M_CAND*8);     // u64[2][8192] packed (score|8191-cp)
static constexpr size_t OFF_SBOX  = alignup(OFF_SKEY + 2ull*8192*8);      // f64[2][4741][4]
static constexpr size_t OFF_SSC   = alignup(OFF_SBOX + 2ull*M_CAND*4*8);  // f64[2][4741]
static constexpr size_t OFF_MASK  = alignup(OFF_SSC + 2ull*M_CAND*8);     // u64[2][4800][75]
static constexpr size_t OFF_WB    = alignup(OFF_MASK + 2ull*4800*75*8);   // bf16[9][8][256][32]
static constexpr size_t OFF_WT    = alignup(OFF_WB + 589824ull*2);        // f32[2304][256] transposed conv w
static constexpr size_t WS_NEED   = OFF_WT + 589824ull*4;                 // ~12.7 MB

__device__ __forceinline__ u64 ordkey(double s){
  u64 b = (u64)__double_as_longlong(s);
  return b ^ ((b >> 63) ? 0xFFFFFFFFFFFFFFFFULL : 0x8000000000000000ULL);
}
__device__ __forceinline__ u32 ordkey32(float s){
  u32 b = __float_as_uint(s);
  return b ^ ((b >> 31) ? 0xFFFFFFFFu : 0x80000000u);
}
__device__ __forceinline__ short bf16rne(float f){
  u32 u = __float_as_uint(f);
  u32 r = (u + 0x7FFFu + ((u >> 16) & 1u)) >> 16;
  return (short)r;
}

// ---------------- K0: prep — counters, sort padding, bf16 weight pack, fp32 weight transpose ----
__global__ __launch_bounds__(256) void k_prep(const float* __restrict__ cw,
                                              short* __restrict__ wb2, float* __restrict__ wT,
                                              u32* cnt, u64* skey){
  int t = blockIdx.x*256 + threadIdx.x;   // grid = 2304*256 = 589824 exactly
  if (t < 64) cnt[t] = 0;
  const int npad = 8192 - M_CAND;
  if (t < 2*npad){
    int img = t / npad;
    int j = M_CAND + (t - img*npad);
    skey[(size_t)img*8192 + j] = 0ULL;   // sorts after every real entry
  }
  // bf16 MFMA pack: [tap][chunk][n][ci32]
  {
    int ci = t & 31, n = (t >> 5) & 255, chunk = (t >> 13) & 7, tap = t >> 16;
    int cig = chunk*32 + ci;
    int ky = tap/3, kx = tap - ky*3;
    wb2[t] = bf16rne(cw[((size_t)(n*256 + cig)*3 + ky)*3 + kx]);
  }
  // fp32 transpose for recompute: wT[k*256+co] = cw[co*2304+k]
  {
    int k = t >> 8, co = t & 255;
    wT[t] = cw[(size_t)co*2304 + k];
  }
}

// ---------------- K1: bf16 MFMA implicit-GEMM conv3x3 + ReLU + obj 1x1 (approx) ----
// ALL levels in one launch; block: 512 thr = 8 waves; 64-pixel strip at row y.
// A-tile in LDS, pitch 128 shorts + XOR granule swizzle (conflict-free b128 reads);
// B (weights) streamed directly from global (L2-resident), no inner barriers.
__global__ __launch_bounds__(512) void k_convb(
    const float* __restrict__ f2, const float* __restrict__ f3,
    const float* __restrict__ f4, const float* __restrict__ f5,
    const float* __restrict__ f6, const short* __restrict__ wb2,
    const float* __restrict__ cb, const float* __restrict__ ow,
    const float* __restrict__ ob, float* __restrict__ ascore)
{
  __shared__ __align__(16) short Ap[198*128];   // [r(pixel)][ci swizzled granules] 49.5KB
  __shared__ float ps[192];                     // [3][64] partial scores
  const int tid = threadIdx.x;
  int bid = blockIdx.x;
  int l = 0;
  while (bid >= c_PRE[l+1]) ++l;
  bid -= c_PRE[l];
  const int W = c_W[l], H = c_H[l], nx = c_NX[l];
  const int xb = bid % nx; int rem = bid / nx;
  const int y = rem % H; const int img = rem / H;
  const int x0 = xb*64;
  const size_t HW = (size_t)H*W;
  const float* fl = (l==0)?f2:(l==1)?f3:(l==2)?f4:(l==3)?f5:f6;
  const float* fb = fl + (size_t)img*256*HW;
  for (int e=tid;e<192;e+=512) ps[e]=0.f;

  const int wid = tid>>6, lane = tid&63;
  const int wr = wid>>2, wc = wid&3;
  const int l15 = lane&15, lg = lane>>4;

  f32x4 acc[2][4];
  #pragma unroll
  for(int a=0;a<2;a++)
    #pragma unroll
    for(int b=0;b<4;b++) acc[a][b] = (f32x4){0.f,0.f,0.f,0.f};

  for (int half=0; half<2; half++){
    __syncthreads();   // previous-half reads done before overwrite
    // stage A: 64 ci-pairs x (3 ry x 66 cx); both global streams coalesced over cx;
    // packed u32 writes at swizzled granule position.
    for (int e=tid; e<12672; e+=512){
      int cp = e/198, r = e - cp*198;          // r = ry*66+cx
      int ci = cp<<1;
      int ry = r/66, cx = r - ry*66;
      int yy = y + ry - 1, xx = x0 + cx - 1;
      float v0 = 0.f, v1 = 0.f;
      if (yy>=0 && yy<H && xx>=0 && xx<W){
        const float* fp = fb + (size_t)(half*128+ci)*HW + (size_t)yy*W + xx;
        v0 = fp[0]; v1 = fp[HW];
      }
      u32 pk = (u32)(unsigned short)bf16rne(v0) | ((u32)(unsigned short)bf16rne(v1) << 16);
      int pos = (((ci>>3) ^ (r&7))<<3) + (ci&7);
      *(u32*)(Ap + r*128 + pos) = pk;
    }
    __syncthreads();
    for (int tap=0; tap<9; tap++){
      const int kyy = tap/3, kxx = tap - kyy*3;
      #pragma unroll
      for (int c2=0; c2<4; c2++){
        // B fragments direct from global (coalesced 16B/lane, L2-hit)
        const short* bs = wb2 + (((tap<<3) + (half<<2) + c2) << 13) + (lg<<3);
        bf16x8 b0 = *(const bf16x8*)(bs + ((wc*64 +  0 + l15)<<5));
        bf16x8 b1 = *(const bf16x8*)(bs + ((wc*64 + 16 + l15)<<5));
        bf16x8 b2 = *(const bf16x8*)(bs + ((wc*64 + 32 + l15)<<5));
        bf16x8 b3 = *(const bf16x8*)(bs + ((wc*64 + 48 + l15)<<5));
        const int colb = kyy*66 + wr*32 + l15 + kxx;
        const int swz = (((c2<<2) + lg) ^ (colb&7)) << 3;
        bf16x8 a0 = *(const bf16x8*)(Ap + colb*128 + swz);
        bf16x8 a1 = *(const bf16x8*)(Ap + (colb+16)*128 + swz);
        acc[0][0] = __builtin_amdgcn_mfma_f32_16x16x32_bf16(a0, b0, acc[0][0], 0,0,0);
        acc[1][0] = __builtin_amdgcn_mfma_f32_16x16x32_bf16(a1, b0, acc[1][0], 0,0,0);
        acc[0][1] = __builtin_amdgcn_mfma_f32_16x16x32_bf16(a0, b1, acc[0][1], 0,0,0);
        acc[1][1] = __builtin_amdgcn_mfma_f32_16x16x32_bf16(a1, b1, acc[1][1], 0,0,0);
        acc[0][2] = __builtin_amdgcn_mfma_f32_16x16x32_bf16(a0, b2, acc[0][2], 0,0,0);
        acc[1][2] = __builtin_amdgcn_mfma_f32_16x16x32_bf16(a1, b2, acc[1][2], 0,0,0);
        acc[0][3] = __builtin_amdgcn_mfma_f32_16x16x32_bf16(a0, b3, acc[0][3], 0,0,0);
        acc[1][3] = __builtin_amdgcn_mfma_f32_16x16x32_bf16(a1, b3, acc[1][3], 0,0,0);
      }
    }
  }
  // epilogue: bias + relu + obj 1x1 (fp32), reduce over n
  float p[3][2][4];
  #pragma unroll
  for (int a=0;a<3;a++)
    #pragma unroll
    for(int mf=0;mf<2;mf++)
      #pragma unroll
      for(int r=0;r<4;r++) p[a][mf][r]=0.f;
  #pragma unroll
  for (int nf=0; nf<4; nf++){
    int n = wc*64 + nf*16 + l15;
    float cbn = cb[n];
    float w0 = ow[n], w1 = ow[256+n], w2 = ow[512+n];
    #pragma unroll
    for (int mf=0; mf<2; mf++)
      #pragma unroll
      for (int r=0;r<4;r++){
        float t = acc[mf][nf][r] + cbn;
        t = t>0.f ? t : 0.f;
        p[0][mf][r] += w0*t; p[1][mf][r] += w1*t; p[2][mf][r] += w2*t;
      }
  }
  #pragma unroll
  for (int a=0;a<3;a++)
    #pragma unroll
    for (int mf=0;mf<2;mf++)
      #pragma unroll
      for (int r=0;r<4;r++){
        float v = p[a][mf][r];
        v += __shfl_xor(v, 1); v += __shfl_xor(v, 2);
        v += __shfl_xor(v, 4); v += __shfl_xor(v, 8);
        p[a][mf][r] = v;
      }
  if (l15 == 0){
    #pragma unroll
    for (int a=0;a<3;a++)
      #pragma unroll
      for (int mf=0;mf<2;mf++)
        #pragma unroll
        for (int r=0;r<4;r++)
          atomicAdd(&ps[a*64 + wr*32 + mf*16 + lg*4 + r], p[a][mf][r]);
  }
  __syncthreads();
  float* so = ascore + c_SCOFF[l] + (size_t)img*HW*3;
  for (int e=tid; e<192; e+=512){
    int a = e>>6, px = e&63;
    int xg = x0 + px;
    if (xg < W) so[((size_t)y*W + xg)*3 + a] = ps[e] + ob[a];
  }
}

// ---------------- K2: per-(level,image) radix-select of K1-th largest fp32 key ----------------
__global__ __launch_bounds__(1024) void k_radix32(const float* __restrict__ ascore,
                                                  u32* __restrict__ thr, u32* __restrict__ quota)
{
  const int u = blockIdx.x, l = u >> 1, img = u & 1;
  const int n = c_S[l], k = c_K1[l];
  const int tid = threadIdx.x;
  if (n <= k){ if (tid==0){ thr[u]=0u; quota[u]=0xFFFFFFFFu; } return; }
  const float* sc = ascore + c_SCOFF[l] + (size_t)img*n;
  __shared__ u32 hist[2048];
  __shared__ u32 grp[32];
  __shared__ u32 s_pref;
  __shared__ u32 s_rem;
  if (tid==0){ s_pref=0u; s_rem=(u32)k; }
  const int shifts[3] = {21,10,0};
  const int bitsA[3]  = {11,11,10};
  for (int p=0;p<3;p++){
    const int nb = 1 << bitsA[p];
    for (int i=tid;i<nb;i+=1024) hist[i]=0u;
    __syncthreads();
    const u32 pref = s_pref;
    const int sh = shifts[p], hb = bitsA[p];
    for (int i=tid;i<n;i+=1024){
      u32 key = ordkey32(sc[i]);
      bool m = (p==0) || ((key >> (sh+hb)) == pref);
      if (m) atomicAdd(&hist[(key>>sh) & (u32)(nb-1)], 1u);
    }
    __syncthreads();
    const int per = nb >> 5;
    if (tid < 32){ u32 s=0; for (int q=0;q<per;q++) s += hist[tid*per+q]; grp[tid]=s; }
    __syncthreads();
    if (tid==0){
      u32 rem = s_rem, cum = 0;
      int g = 31;
      for (; g>0; g--){ if (cum + grp[g] >= rem) break; cum += grp[g]; }
      int b = (g+1)*per - 1;
      for (; b > g*per; b--){ if (cum + hist[b] >= rem) break; cum += hist[b]; }
      s_pref = (s_pref << hb) | (u32)b;
      s_rem = rem - cum;
    }
    __syncthreads();
  }
  if (tid==0){ thr[u] = s_pref; quota[u] = s_rem; }
}

// ---------------- K2b: compact selected indices ----------------
__global__ __launch_bounds__(256) void k_compact32(const float* __restrict__ ascore,
    const u32* __restrict__ thr, const u32* __restrict__ quota,
    u32* __restrict__ cnt, u32* __restrict__ sel)
{
  const int u = blockIdx.y, l = u >> 1, img = u & 1;
  const int n = c_S[l];
  const int i = blockIdx.x*256 + threadIdx.x;
  if (i >= n) return;
  const float* sc = ascore + c_SCOFF[l] + (size_t)img*n;
  u32 key = ordkey32(sc[i]);
  u32 q = quota[u];
  bool take = false;
  if (q == 0xFFFFFFFFu) take = true;           // n <= k: take all
  else {
    u32 t = thr[u];
    if (key > t) take = true;
    else if (key == t){ if (atomicAdd(&cnt[16+u],1u) < q) take = true; }
  }
  if (take){ u32 p = atomicAdd(&cnt[u],1u); if (p < 1024u) sel[u*1024 + p] = (u32)i; }
}

// ---------------- K3: fp64-MFMA recompute with RUNTIME-PROBED fragment layout ----------------
// block = 16 entries (M); 256 thr = 4 waves; each wave owns 64 co (4 n-tiles of 16).
// Layout discovery: 3 probe MFMAs tell us A/B lane mappings and exact D (row,col) per reg.
__global__ __launch_bounds__(256) void k_recompute(
    const float* __restrict__ f2, const float* __restrict__ f3,
    const float* __restrict__ f4, const float* __restrict__ f5,
    const float* __restrict__ f6,
    const float* __restrict__ wT, const float* __restrict__ cb,
    const float* __restrict__ ow, const float* __restrict__ ob,
    const float* __restrict__ dwt, const float* __restrict__ db,
    const u32* __restrict__ sel, const u32* __restrict__ cnt,
    double* __restrict__ rsc, double* __restrict__ rdl)
{
  const int u = blockIdx.y, l = u >> 1, img = u & 1;
  const int j0 = blockIdx.x * 16;
  const int cu = (int)cnt[u];
  if (j0 >= cu) return;
  const int W = c_W[l], H = c_H[l];
  const size_t HW = (size_t)W*H;
  const float* fl = (l==0)?f2:(l==1)?f3:(l==2)?f4:(l==3)?f5:f6;
  const float* fb = fl + (size_t)img*256*HW;
  __shared__ __align__(16) float spA[576*17];   // 39.2KB, [k within chunk][entry] pitch 17
  __shared__ int sx[16], sy[16], sa[16];
  const int tid = threadIdx.x;
  if (tid < 16){
    int j = j0 + tid; int ok = (j < cu) ? 1 : 0;
    u32 i = ok ? sel[u*1024 + j] : 0u;
    int pos = (int)(i/3u);
    sa[tid] = (int)i - pos*3; sx[tid] = pos % W; sy[tid] = pos / W;
  }
  const int wid = tid >> 6, lane = tid & 63;

  // ---- layout probes (3 MFMAs) ----
  const f64x4 pz = (f64x4){0.0,0.0,0.0,0.0};
  f64x4 p1 = __builtin_amdgcn_mfma_f64_16x16x4f64((double)lane, 1.0, pz, 0,0,0);
  const double v0 = __shfl(p1[0], 0);
  const bool isA1 = (v0 > 50.0);
  const double aD = isA1 ? ((lane<16)?1.0:0.0) : (((lane&3)==0)?1.0:0.0);
  f64x4 p2 = __builtin_amdgcn_mfma_f64_16x16x4f64(aD, (double)lane, pz, 0,0,0);
  const bool own1 = (p2[0]==1.0)||(p2[1]==1.0)||(p2[2]==1.0)||(p2[3]==1.0);
  const bool isB1 = (__ballot(own1) != 0ull);
  const double aI = (double)(isA1 ? (lane&15) : (lane>>2));
  const double bD = isB1 ? ((lane<16)?1.0:0.0) : (((lane&3)==0)?1.0:0.0);
  f64x4 p3 = __builtin_amdgcn_mfma_f64_16x16x4f64(aI, bD, pz, 0,0,0);
  int row_[4], col_[4];
  const double cs = isB1 ? 1.0 : 0.25;
  #pragma unroll
  for (int r=0;r<4;r++){ col_[r] = (int)(p2[r]*cs); row_[r] = (int)p3[r]; }
  const int mrow = isA1 ? (lane&15) : (lane>>2);
  const int kA   = isA1 ? (lane>>4) : (lane&3);
  const int jB   = isB1 ? (lane&15) : (lane>>2);
  const int kB   = isB1 ? (lane>>4) : (lane&3);

  f64x4 acc[4];
  #pragma unroll
  for (int nt=0;nt<4;nt++) acc[nt] = pz;
  __syncthreads();
  for (int ci0=0; ci0<256; ci0+=64){
    for (int el=tid; el<9216; el+=256){
      int e = el/576, r = el - e*576;
      int ci = r/9, q = r - ci*9, ky = q/3, kx = q - ky*3;
      int yy = sy[e]+ky-1, xx = sx[e]+kx-1;
      float v = 0.0f;
      if (yy>=0 && yy<H && xx>=0 && xx<W) v = fb[(size_t)(ci0+ci)*HW + (size_t)yy*W + xx];
      spA[r*17 + e] = v;
    }
    __syncthreads();
    const float* wb = wT + (size_t)(ci0*9)*256 + (wid<<6) + jB;
    #pragma unroll 2
    for (int kt=0; kt<144; kt++){
      double a = (double)spA[(kt*4 + kA)*17 + mrow];
      const float* bp = wb + (size_t)(kt*4 + kB)*256;
      #pragma unroll
      for (int nt=0; nt<4; nt++){
        double b = (double)bp[nt*16];
        acc[nt] = __builtin_amdgcn_mfma_f64_16x16x4f64(a, b, acc[nt], 0,0,0);
      }
    }
    __syncthreads();
  }
  // epilogue: bias + relu into tl2[16][257] f64 (aliased onto spA; all reads drained)
  double* tl2 = (double*)spA;
  #pragma unroll
  for (int nt=0; nt<4; nt++){
    #pragma unroll
    for (int r=0;r<4;r++){
      const int co = (wid<<6) + nt*16 + col_[r];
      double t = acc[nt][r] + (double)cb[co];
      tl2[row_[r]*257 + co] = t > 0.0 ? t : 0.0;
    }
  }
  __syncthreads();
  if (tid < 80){
    int e = tid/5, q = tid - e*5;
    if (j0 + e < cu){
      int a = sa[e];
      const float* wv = (q==0) ? (ow + a*256) : (dwt + (size_t)(a*4 + q-1)*256);
      double bias = (q==0) ? (double)ob[a] : (double)db[a*4 + q-1];
      double s = 0.0;
      for (int c=0;c<256;c++) s += (double)wv[c]*tl2[e*257 + c];
      s += bias;
      int j = j0 + e;
      if (q==0) rsc[(size_t)u*1024 + j] = s;
      else      rdl[((size_t)u*1024 + j)*4 + (q-1)] = s;
    }
  }
}

// ---------------- K3b: per-(level,image) bitonic sort of 1024 by exact fp64 score ----------------
__global__ __launch_bounds__(256) void k_sort1024(const double* __restrict__ rsc,
    const u32* __restrict__ cnt, u32* __restrict__ sord)
{
  const int u = blockIdx.x;
  const int cu = (int)cnt[u];
  const int tid = threadIdx.x;
  __shared__ u64 kk[1024];
  __shared__ u32 pp[1024];
  for (int i=tid;i<1024;i+=256){
    if (i < cu){ kk[i] = ordkey(rsc[(size_t)u*1024 + i]); pp[i] = (u32)i; }
    else       { kk[i] = 0ULL; pp[i] = 0xFFFFFFFFu; }
  }
  __syncthreads();
  for (int k=2;k<=1024;k<<=1){
    for (int j=k>>1;j>0;j>>=1){
      for (int i=tid;i<1024;i+=256){
        int l2 = i ^ j;
        if (l2 > i){
          u64 ka = kk[i], kb = kk[l2];
          u32 ia = pp[i], ib = pp[l2];
          bool before = (ka > kb) || (ka == kb && ia < ib);
          bool up = (i & k) == 0;
          if (up ? !before : before){
            kk[i]=kb; kk[l2]=ka; pp[i]=ib; pp[l2]=ia;
          }
        }
      }
      __syncthreads();
    }
  }
  for (int i=tid;i<1024;i+=256) sord[(size_t)u*1024 + i] = pp[i];
}

// ---------------- K4: decode boxes (exact mixed fp32/fp64 like reference) ----------------
__global__ __launch_bounds__(256) void k_decode(
    const double* __restrict__ rsc, const double* __restrict__ rdl,
    const u32* __restrict__ sel, const u32* __restrict__ sord,
    double* __restrict__ cbox, double* __restrict__ csc,
    u64* __restrict__ skey, u32* __restrict__ cnt)
{
#pragma clang fp contract(off)
  const int u = blockIdx.y, l = u >> 1, img = u & 1;
  const int slot = blockIdx.x*256 + threadIdx.x;
  if (slot >= c_K2[l]) return;
  const u32 entry = sord[(size_t)u*1024 + slot];
  const u32 idx = sel[u*1024 + entry];
  const double s = rsc[(size_t)u*1024 + entry];
  const double d0 = rdl[((size_t)u*1024+entry)*4+0], d1 = rdl[((size_t)u*1024+entry)*4+1];
  double d2 = rdl[((size_t)u*1024+entry)*4+2], d3 = rdl[((size_t)u*1024+entry)*4+3];
  const int pos = (int)(idx/3u), a = (int)idx - pos*3;
  const int W = c_W[l];
  const int x = pos % W, y = pos / W;
  const double rr = (a==0) ? 0.5 : ((a==1) ? 1.0 : 2.0);
  const double sz = (double)c_SZ[l];
  const double wa = sqrt(sz*sz/rr);
  const double ha = wa*rr;
  const float xs = (float)(x*c_STR[l]);
  const float ys = (float)(y*c_STR[l]);
  const float ax0 = xs + (float)(-0.5*wa);
  const float ax1 = xs + (float)( 0.5*wa);
  const float ay0 = ys + (float)(-0.5*ha);
  const float ay1 = ys + (float)( 0.5*ha);
  const float wf = ax1 - ax0;
  const float hf = ay1 - ay0;
  const float cxf = ax0 + 0.5f*wf;
  const float cyf = ay0 + 0.5f*hf;
  const double Wd = (double)wf, Hd = (double)hf, CX = (double)cxf, CY = (double)cyf;
  const double SCLAMP = 4.135166556742356;   // log(1000/16)
  if (d2 > SCLAMP) d2 = SCLAMP;
  if (d3 > SCLAMP) d3 = SCLAMP;
  double pcx = d0*Wd; pcx = pcx + CX;
  double pcy = d1*Hd; pcy = pcy + CY;
  const double pw = exp(d2)*Wd;
  const double ph = exp(d3)*Hd;
  double x0 = pcx - 0.5*pw;
  double y0 = pcy - 0.5*ph;
  double x1 = pcx + 0.5*pw;
  double y1 = pcy + 0.5*ph;
  x0 = fmin(fmax(x0, 0.0), 1216.0);
  x1 = fmin(fmax(x1, 0.0), 1216.0);
  y0 = fmin(fmax(y0, 0.0), 800.0);
  y1 = fmin(fmax(y1, 0.0), 800.0);
  const bool valid = (x1 - x0 > 0.0) && (y1 - y0 > 0.0);
  const double sm = valid ? s : -1e9;
  const int cp = c_LOFF[l] + slot;
  double* cb = cbox + ((size_t)img*M_CAND + cp)*4;
  cb[0]=x0; cb[1]=y0; cb[2]=x1; cb[3]=y1;
  csc[(size_t)img*M_CAND + cp] = sm;
  // packed key: truncated fp64 ordkey (13 low mantissa bits dropped; resolution
  // ~2e-12 rel << 1e-4 score gaps) | (8191-cp) => sort desc == (score desc, cp asc)
  skey[(size_t)img*8192 + cp] = (ordkey(sm) & ~(u64)0x1FFF) | (u64)(8191 - cp);
  if (valid) atomicAdd(&cnt[32+img], 1u);
}

// ---------------- K5: per-image bitonic sort of packed keys, fully in LDS ----------------
__global__ __launch_bounds__(1024) void k_sort(u64* __restrict__ key)
{
  const int img = blockIdx.x;
  u64* g = key + (size_t)img*8192;
  __shared__ u64 kk[8192];   // 64KB
  const int tid = threadIdx.x;
  for (int i=tid;i<8192;i+=1024) kk[i]=g[i];
  __syncthreads();
  for (int k=2;k<=8192;k<<=1){
    for (int j=k>>1;j>0;j>>=1){
      for (int i=tid;i<8192;i+=1024){
        int l = i ^ j;
        if (l > i){
          u64 ka = kk[i], kb = kk[l];
          bool before = (ka > kb);
          bool up = (i & k) == 0;
          if (up ? !before : before){ kk[i]=kb; kk[l]=ka; }
        }
      }
      __syncthreads();
    }
  }
  for (int i=tid;i<8192;i+=1024) g[i]=kk[i];
}

// ---------------- K5b: gather sorted boxes/scores ----------------
__global__ __launch_bounds__(256) void k_gather(const u64* __restrict__ skey,
    const double* __restrict__ cbox, const double* __restrict__ csc,
    double* __restrict__ sbox, double* __restrict__ ssc)
{
  int t = blockIdx.x*256 + threadIdx.x;
  if (t >= 2*M_CAND) return;
  int img = t / M_CAND, j = t - img*M_CAND;
  u32 b = 8191u - (u32)(skey[(size_t)img*8192 + j] & 0x1FFFull);
  const double* cb = cbox + ((size_t)img*M_CAND + b)*4;
  double* sb = sbox + ((size_t)img*M_CAND + j)*4;
  sb[0]=cb[0]; sb[1]=cb[1]; sb[2]=cb[2]; sb[3]=cb[3];
  ssc[(size_t)img*M_CAND + j] = csc[(size_t)img*M_CAND + b];
}

// ---------------- K6: pairwise IoU suppression bitmask ----------------
__global__ __launch_bounds__(256) void k_iou(const double* __restrict__ sbox, u64* __restrict__ mask)
{
#pragma clang fp contract(off)
  const int jb = blockIdx.x, ib = blockIdx.y, img = blockIdx.z;
  if (jb < ib) return;
  __shared__ double ibx[64][4];
  const int tid = threadIdx.x;
  const int lane = tid & 63, wv = tid >> 6;
  if (tid < 64){
    int ig = ib*64 + tid;
    if (ig < M_CAND){
      const double* b = sbox + ((size_t)img*M_CAND + ig)*4;
      ibx[tid][0]=b[0]; ibx[tid][1]=b[1]; ibx[tid][2]=b[2]; ibx[tid][3]=b[3];
    } else { ibx[tid][0]=0; ibx[tid][1]=0; ibx[tid][2]=0; ibx[tid][3]=0; }
  }
  const int jg = jb*64 + lane;
  double jx0=0,jy0=0,jx1=0,jy1=0;
  if (jg < M_CAND){
    const double* b = sbox + ((size_t)img*M_CAND + jg)*4;
    jx0=b[0]; jy0=b[1]; jx1=b[2]; jy1=b[3];
  }
  const double ja = (jx1-jx0)*(jy1-jy0);
  __syncthreads();
  for (int s=0;s<16;s++){
    const int il = wv*16 + s;
    const int ig = ib*64 + il;
    double bx0=ibx[il][0], by0=ibx[il][1], bx1=ibx[il][2], by1=ibx[il][3];
    double lt0 = bx0 > jx0 ? bx0 : jx0;
    double lt1 = by0 > jy0 ? by0 : jy0;
    double rb0 = bx1 < jx1 ? bx1 : jx1;
    double rb1 = by1 < jy1 ? by1 : jy1;
    double w = rb0-lt0; if (w<0.0) w=0.0;
    double h = rb1-lt1; if (h<0.0) h=0.0;
    double inter = w*h;
    double ia = (bx1-bx0)*(by1-by0);
    double un = ia + ja - inter; if (un < 1e-9) un = 1e-9;
    bool bit = (jg > ig) && (jg < M_CAND) && (inter/un > 0.7);
    u64 m = __ballot(bit);
    if (lane == 0) mask[((size_t)img*4800 + ig)*75 + jb] = m;
  }
}

// ---------------- K7: chunked greedy scan + output ----------------
__global__ __launch_bounds__(256) void k_nms(const u64* __restrict__ mask,
    const double* __restrict__ sbox, const double* __restrict__ ssc,
    const u32* __restrict__ cnt, float* __restrict__ out)
{
  const int img = blockIdx.x;
  const int tid = threadIdx.x;
  __shared__ u64 remv[75];
  __shared__ u64 diag[64];
  __shared__ int keep[1000];
  __shared__ int ck[64];
  __shared__ int s_kc, s_nk, s_done;
  if (tid < 75) remv[tid] = 0ULL;
  if (tid == 0){ s_kc = 0; s_done = 0; }
  int vc = (int)cnt[32+img]; if (vc > M_CAND) vc = M_CAND;
  const u64* mrow = mask + (size_t)img*4800*75;
  __syncthreads();
  for (int c=0; c<75; c++){
    if (c*64 >= vc) break;
    if (tid < 64) diag[tid] = mrow[(size_t)(c*64+tid)*75 + c];
    __syncthreads();
    if (tid == 0){
      u64 w = remv[c];
      int kc = s_kc, nk = 0;
      int lim = vc - c*64; if (lim > 64) lim = 64;
      for (int k=0;k<lim;k++){
        if (!((w >> k) & 1ULL)){
          int idx = c*64 + k;
          keep[kc] = idx;
          ck[nk++] = idx;
          kc++;
          if (kc >= 1000) break;
          w |= diag[k];
        }
      }
      s_kc = kc; s_nk = nk;
      if (kc >= 1000) s_done = 1;
    }
    __syncthreads();
    if (s_done) break;
    const int nk = s_nk;
    if (nk > 0){
      for (int c2 = c+1+tid; c2 < 75; c2 += 256){
        u64 a = remv[c2];
        for (int q=0;q<nk;q++) a |= mrow[(size_t)ck[q]*75 + c2];
        remv[c2] = a;
      }
    }
    __syncthreads();
  }
  __syncthreads();
  int kc = s_kc; if (kc > 1000) kc = 1000;
  for (int r = tid; r < 1000; r += 256){
    float v0=0.f,v1=0.f,v2=0.f,v3=0.f,v4=-1e9f;
    if (r < kc){
      int idx = keep[r];
      const double* b = sbox + ((size_t)img*M_CAND + idx)*4;
      v0=(float)b[0]; v1=(float)b[1]; v2=(float)b[2]; v3=(float)b[3];
      v4=(float)ssc[(size_t)img*M_CAND + idx];
    }
    float* o = out + ((size_t)img*1000 + r)*5;
    o[0]=v0; o[1]=v1; o[2]=v2; o[3]=v3; o[4]=v4;
  }
}

// ---------------- host ----------------
extern "C" void kernel_launch(void* const* d_in, const int* in_sizes, int n_in,
                              void* d_out, int out_size, void* d_ws, size_t ws_size,
                              hipStream_t stream)
{
  const float* feat[5];
  for (int i=0;i<5;i++) feat[i] = (const float*)d_in[i];
  const float* cw  = (const float*)d_in[5];
  const float* cb  = (const float*)d_in[6];
  const float* ow  = (const float*)d_in[7];
  const float* ob  = (const float*)d_in[8];
  const float* dwt = (const float*)d_in[9];
  const float* db  = (const float*)d_in[10];
  float* out = (float*)d_out;
  char* ws = (char*)d_ws;
  if (ws_size < WS_NEED) return;

  float*  ascore = (float*)(ws + OFF_ASC);
  u32*    thr    = (u32*)(ws + OFF_THR);
  u32*    quota  = (u32*)(ws + OFF_QUOTA);
  u32*    cnt    = (u32*)(ws + OFF_CNT);
  u32*    sel    = (u32*)(ws + OFF_SEL);
  double* rsc    = (double*)(ws + OFF_RSC);
  double* rdl    = (double*)(ws + OFF_RDL);
  u32*    sord   = (u32*)(ws + OFF_SORD);
  double* cbox   = (double*)(ws + OFF_CBOX);
  double* csc    = (double*)(ws + OFF_CSC);
  u64*    skey   = (u64*)(ws + OFF_SKEY);
  double* sbox   = (double*)(ws + OFF_SBOX);
  double* ssc    = (double*)(ws + OFF_SSC);
  u64*    mask   = (u64*)(ws + OFF_MASK);
  short*  wb2    = (short*)(ws + OFF_WB);
  float*  wT     = (float*)(ws + OFF_WT);

  k_prep<<<2304,256,0,stream>>>(cw, wb2, wT, cnt, skey);
  k_convb<<<2876,512,0,stream>>>(feat[0],feat[1],feat[2],feat[3],feat[4],
                                 wb2, cb, ow, ob, ascore);
  k_radix32<<<10,1024,0,stream>>>(ascore, thr, quota);
  k_compact32<<<dim3(713,10),256,0,stream>>>(ascore, thr, quota, cnt, sel);
  k_recompute<<<dim3(64,10),256,0,stream>>>(feat[0],feat[1],feat[2],feat[3],feat[4],
                                            wT, cb, ow, ob, dwt, db, sel, cnt, rsc, rdl);
  k_sort1024<<<10,256,0,stream>>>(rsc, cnt, sord);
  k_decode<<<dim3(4,10),256,0,stream>>>(rsc, rdl, sel, sord, cbox, csc, skey, cnt);
  k_sort<<<2,1024,0,stream>>>(skey);
  k_gather<<<38,256,0,stream>>>(skey, cbox, csc, sbox, ssc);
  k_iou<<<dim3(75,75,2),256,0,stream>>>(sbox, mask);
  k_nms<<<2,256,0,stream>>>(mask, sbox, ssc, cnt, out);
}